// Round 2
// baseline (5661.354 us; speedup 1.0000x reference)
//
#include <hip/hip_runtime.h>
#include <hip/hip_bf16.h>
#include <cstdint>

// Problem constants (B=4, S=4096, D=1024)
#define NR      16384   // B*S rows
#define DMODEL  1024
#define DINNER  2048
#define SEQ     4096

__device__ __forceinline__ float phi_f(float t)  { return t > 0.0f ? t + 1.0f : __expf(t); }
__device__ __forceinline__ float silu_f(float t) { return t / (1.0f + __expf(-t)); }

#define FMA4(dst, s, vv)                      \
    dst.x = fmaf((s), (vv).x, dst.x);         \
    dst.y = fmaf((s), (vv).y, dst.y);         \
    dst.z = fmaf((s), (vv).z, dst.z);         \
    dst.w = fmaf((s), (vv).w, dst.w);

// ---------------- 1. per-row RMS scale: scale[r] = rsqrt(mean(x[r]^2)+eps) ----
__global__ __launch_bounds__(256) void rms_scale_k(const float* __restrict__ x,
                                                   float* __restrict__ scale)
{
    const int r = blockIdx.x;
    const float4 v = *(const float4*)(x + (size_t)r * DMODEL + threadIdx.x * 4);
    float s = v.x * v.x + v.y * v.y + v.z * v.z + v.w * v.w;
#pragma unroll
    for (int m = 1; m < 64; m <<= 1) s += __shfl_xor(s, m);
    __shared__ float wsum[4];
    const int lane = threadIdx.x & 63, w = threadIdx.x >> 6;
    if (lane == 0) wsum[w] = s;
    __syncthreads();
    if (threadIdx.x == 0) {
        const float tot = wsum[0] + wsum[1] + wsum[2] + wsum[3];
        scale[r] = rsqrtf(tot * (1.0f / DMODEL) + 1e-5f);
    }
}

// ---------------- 2. fp32 GEMM, 128x128 tile, 8x8 microtile, BK=16 -----------
// EPI: 0 none, 1 q-epilogue phi(t)*0.125, 2 k-epilogue phi(t), 3 add addx[m][n]
// If rowscale != nullptr: A[r][k] := A[r][k] * rowscale[r] * normw[k]  (fused rmsnorm)
template <int EPI>
__global__ __launch_bounds__(256) void gemm_k(const float* __restrict__ A,
                                              const float* __restrict__ Bw,
                                              float* __restrict__ C,
                                              int M, int N, int K,
                                              const float* __restrict__ rowscale,
                                              const float* __restrict__ normw,
                                              const float* __restrict__ addx)
{
    __shared__ float As[16][128];
    __shared__ float Bs[16][128];

    const int t  = threadIdx.x;
    const int bm = blockIdx.y * 128;
    const int bn = blockIdx.x * 128;
    const int tx = t & 15, ty = t >> 4;

    // staging coordinates
    const int ar0 = t >> 2;          // A rows ar0 and ar0+64
    const int ac  = (t & 3) * 4;     // A cols ac..ac+3 (within k-tile)
    const int br0 = t >> 5;          // B rows br0 and br0+8
    const int bc  = (t & 31) * 4;    // B cols bc..bc+3

    float rs0 = 1.0f, rs1 = 1.0f;
    if (rowscale) { rs0 = rowscale[bm + ar0]; rs1 = rowscale[bm + ar0 + 64]; }

    const float* Aptr0 = A + (size_t)(bm + ar0) * K + ac;
    const float* Aptr1 = A + (size_t)(bm + ar0 + 64) * K + ac;
    const float* Bptr0 = Bw + (size_t)br0 * N + bn + bc;
    const float* Bptr1 = Bw + (size_t)(br0 + 8) * N + bn + bc;

    float acc[8][8];
#pragma unroll
    for (int i = 0; i < 8; ++i)
#pragma unroll
        for (int j = 0; j < 8; ++j) acc[i][j] = 0.0f;

    float4 pa0 = *(const float4*)(Aptr0);
    float4 pa1 = *(const float4*)(Aptr1);
    float4 pb0 = *(const float4*)(Bptr0);
    float4 pb1 = *(const float4*)(Bptr1);
    float4 pnw = make_float4(1.f, 1.f, 1.f, 1.f);
    if (rowscale) pnw = *(const float4*)(normw + ac);

    for (int k0 = 0; k0 < K; k0 += 16) {
        __syncthreads();   // previous tile's compute finished
        float4 wa0 = pa0, wa1 = pa1;
        if (rowscale) {
            wa0.x *= rs0 * pnw.x; wa0.y *= rs0 * pnw.y; wa0.z *= rs0 * pnw.z; wa0.w *= rs0 * pnw.w;
            wa1.x *= rs1 * pnw.x; wa1.y *= rs1 * pnw.y; wa1.z *= rs1 * pnw.z; wa1.w *= rs1 * pnw.w;
        }
        As[ac + 0][ar0] = wa0.x; As[ac + 1][ar0] = wa0.y;
        As[ac + 2][ar0] = wa0.z; As[ac + 3][ar0] = wa0.w;
        As[ac + 0][ar0 + 64] = wa1.x; As[ac + 1][ar0 + 64] = wa1.y;
        As[ac + 2][ar0 + 64] = wa1.z; As[ac + 3][ar0 + 64] = wa1.w;
        *(float4*)&Bs[br0][bc]     = pb0;
        *(float4*)&Bs[br0 + 8][bc] = pb1;

        if (k0 + 16 < K) {   // prefetch next tile while compute runs
            pa0 = *(const float4*)(Aptr0 + k0 + 16);
            pa1 = *(const float4*)(Aptr1 + k0 + 16);
            pb0 = *(const float4*)(Bptr0 + (size_t)(k0 + 16) * N);
            pb1 = *(const float4*)(Bptr1 + (size_t)(k0 + 16) * N);
            if (rowscale) pnw = *(const float4*)(normw + k0 + 16 + ac);
        }
        __syncthreads();

#pragma unroll
        for (int kk = 0; kk < 16; ++kk) {
            float a[8], b[8];
            ((float4*)a)[0] = *(const float4*)&As[kk][ty * 4];
            ((float4*)a)[1] = *(const float4*)&As[kk][64 + ty * 4];
            ((float4*)b)[0] = *(const float4*)&Bs[kk][tx * 4];
            ((float4*)b)[1] = *(const float4*)&Bs[kk][64 + tx * 4];
#pragma unroll
            for (int i = 0; i < 8; ++i)
#pragma unroll
                for (int j = 0; j < 8; ++j)
                    acc[i][j] = fmaf(a[i], b[j], acc[i][j]);
        }
    }

    // epilogue + store
#pragma unroll
    for (int i = 0; i < 8; ++i) {
        const int m = bm + (i < 4 ? ty * 4 + i : 64 + ty * 4 + (i - 4));
#pragma unroll
        for (int half = 0; half < 2; ++half) {
            const int n = bn + (half ? 64 + tx * 4 : tx * 4);
            float4 o;
            o.x = acc[i][half * 4 + 0];
            o.y = acc[i][half * 4 + 1];
            o.z = acc[i][half * 4 + 2];
            o.w = acc[i][half * 4 + 3];
            if (EPI == 1) {
                o.x = phi_f(o.x) * 0.125f; o.y = phi_f(o.y) * 0.125f;
                o.z = phi_f(o.z) * 0.125f; o.w = phi_f(o.w) * 0.125f;
            } else if (EPI == 2) {
                o.x = phi_f(o.x); o.y = phi_f(o.y);
                o.z = phi_f(o.z); o.w = phi_f(o.w);
            } else if (EPI == 3) {
                const float4 xv = *(const float4*)(addx + (size_t)m * N + n);
                o.x += xv.x; o.y += xv.y; o.z += xv.z; o.w += xv.w;
            }
            *(float4*)(C + (size_t)m * N + n) = o;
        }
    }
}

// ---------------- 3. causal depthwise conv + silu, fused with gate (in-place) -
// gate[r][c] := silu(gate[r][c]) * silu(conv_b[c] + sum_j up[r-3+j][c]*conv_w[c][j])
// rows must be a multiple of SEQ; conv never crosses sequence boundary (s = row & 4095).
__global__ __launch_bounds__(256) void conv_gate_k(const float* __restrict__ up,
                                                   float* __restrict__ gate,
                                                   const float* __restrict__ cw,
                                                   const float* __restrict__ cb)
{
    const int idx = blockIdx.x * 256 + threadIdx.x;  // float4 index
    const int row = idx >> 9;
    const int c4  = idx & 511;
    const int s   = row & (SEQ - 1);
    const int c   = c4 * 4;

    const float4 t0 = *(const float4*)(cw + (size_t)(c + 0) * 4);
    const float4 t1 = *(const float4*)(cw + (size_t)(c + 1) * 4);
    const float4 t2 = *(const float4*)(cw + (size_t)(c + 2) * 4);
    const float4 t3 = *(const float4*)(cw + (size_t)(c + 3) * 4);
    const float ta0[4] = {t0.x, t0.y, t0.z, t0.w};
    const float ta1[4] = {t1.x, t1.y, t1.z, t1.w};
    const float ta2[4] = {t2.x, t2.y, t2.z, t2.w};
    const float ta3[4] = {t3.x, t3.y, t3.z, t3.w};

    float4 acc = *(const float4*)(cb + c);
#pragma unroll
    for (int j = 0; j < 4; ++j) {
        const int sj = s - 3 + j;
        if (sj >= 0) {
            const float4 u = *(const float4*)(up + ((size_t)row - 3 + j) * DINNER + c);
            acc.x = fmaf(u.x, ta0[j], acc.x);
            acc.y = fmaf(u.y, ta1[j], acc.y);
            acc.z = fmaf(u.z, ta2[j], acc.z);
            acc.w = fmaf(u.w, ta3[j], acc.w);
        }
    }
    float4 gv = *(const float4*)(gate + (size_t)idx * 4);
    float4 o;
    o.x = silu_f(gv.x) * silu_f(acc.x);
    o.y = silu_f(gv.y) * silu_f(acc.y);
    o.z = silu_f(gv.z) * silu_f(acc.z);
    o.w = silu_f(gv.w) * silu_f(acc.w);
    *(float4*)(gate + (size_t)idx * 4) = o;
}

// ---------------- 4. Hebbian chunked scan --------------------------------------
// 1 block per (b_local, h); blockIdx.x = b_local*16 + h. M[64][64] in LDS.
// Per chunk: sc = tril(q k^T) (regs), y = q M + sc v, M += k^T v.
// sc is spilled into qs after the q-consumers finish (saves 16KB LDS -> 64KB static).
// NOTE: y may alias kk_ (same buffer): chunk ch's k rows are consumed into LDS
// before the same rows are overwritten with y, and blocks touch disjoint slices.
__global__ __launch_bounds__(1024) void hebbian_scan_k(const float* __restrict__ q,
                                                       const float* __restrict__ kk_,
                                                       const float* __restrict__ v,
                                                       float* __restrict__ y)
{
    __shared__ float Ms[4096];
    __shared__ float qs[4096];   // holds q, then reused for sc
    __shared__ float kTs[4096];  // kT[d][c] = k[c][d]
    __shared__ float vs[4096];

    const int t = threadIdx.x;
    const int b = blockIdx.x >> 4;
    const int h = blockIdx.x & 15;

    *(float4*)(Ms + t * 4) = make_float4(0.f, 0.f, 0.f, 0.f);

    const int lr = t >> 4;          // load row
    const int ld = (t & 15) * 4;    // load col group
    const int cw = lr;              // compute row (c for sc/y, d for M-update)
    const int dd = ld;              // compute col group

    const size_t base = (size_t)b * SEQ * DMODEL + (size_t)h * 64;

    for (int ch = 0; ch < 64; ++ch) {
        const size_t g = base + (size_t)(ch * 64 + lr) * DMODEL + ld;
        const float4 q4 = *(const float4*)(q + g);
        const float4 k4 = *(const float4*)(kk_ + g);
        const float4 v4 = *(const float4*)(v + g);
        __syncthreads();            // prev iteration consumers of qs/kTs/vs done
        *(float4*)(qs + lr * 64 + ld) = q4;
        *(float4*)(vs + lr * 64 + ld) = v4;
        kTs[(ld + 0) * 64 + lr] = k4.x;
        kTs[(ld + 1) * 64 + lr] = k4.y;
        kTs[(ld + 2) * 64 + lr] = k4.z;
        kTs[(ld + 3) * 64 + lr] = k4.w;
        __syncthreads();

        // sc[cw][dd..dd+3] = sum_d q[cw][d] * k[dd+i][d], masked to e<=cw (regs)
        float4 sc = make_float4(0.f, 0.f, 0.f, 0.f);
#pragma unroll
        for (int d0 = 0; d0 < 64; d0 += 4) {
            const float4 qv  = *(const float4*)(qs + cw * 64 + d0);
            const float4 k0v = *(const float4*)(kTs + (d0 + 0) * 64 + dd);
            const float4 k1v = *(const float4*)(kTs + (d0 + 1) * 64 + dd);
            const float4 k2v = *(const float4*)(kTs + (d0 + 2) * 64 + dd);
            const float4 k3v = *(const float4*)(kTs + (d0 + 3) * 64 + dd);
            FMA4(sc, qv.x, k0v);
            FMA4(sc, qv.y, k1v);
            FMA4(sc, qv.z, k2v);
            FMA4(sc, qv.w, k3v);
        }
        sc.x = (dd + 0 <= cw) ? sc.x : 0.0f;
        sc.y = (dd + 1 <= cw) ? sc.y : 0.0f;
        sc.z = (dd + 2 <= cw) ? sc.z : 0.0f;
        sc.w = (dd + 3 <= cw) ? sc.w : 0.0f;

        // y1: acc = sum_d q[cw][d]*M[d][dd..]
        float4 acc = make_float4(0.f, 0.f, 0.f, 0.f);
#pragma unroll
        for (int d0 = 0; d0 < 64; d0 += 4) {
            const float4 qv = *(const float4*)(qs + cw * 64 + d0);
            const float4 m0 = *(const float4*)(Ms + (d0 + 0) * 64 + dd);
            const float4 m1 = *(const float4*)(Ms + (d0 + 1) * 64 + dd);
            const float4 m2 = *(const float4*)(Ms + (d0 + 2) * 64 + dd);
            const float4 m3 = *(const float4*)(Ms + (d0 + 3) * 64 + dd);
            FMA4(acc, qv.x, m0);
            FMA4(acc, qv.y, m1);
            FMA4(acc, qv.z, m2);
            FMA4(acc, qv.w, m3);
        }
        __syncthreads();            // all q-reads of qs done; Ms reads done
        *(float4*)(qs + cw * 64 + dd) = sc;   // qs now holds sc
        __syncthreads();

        // y2: acc += sum_e sc[cw][e]*v[e][dd..]
#pragma unroll
        for (int e0 = 0; e0 < 64; e0 += 4) {
            const float4 sv = *(const float4*)(qs + cw * 64 + e0);
            const float4 v0 = *(const float4*)(vs + (e0 + 0) * 64 + dd);
            const float4 v1 = *(const float4*)(vs + (e0 + 1) * 64 + dd);
            const float4 v2 = *(const float4*)(vs + (e0 + 2) * 64 + dd);
            const float4 v3 = *(const float4*)(vs + (e0 + 3) * 64 + dd);
            FMA4(acc, sv.x, v0);
            FMA4(acc, sv.y, v1);
            FMA4(acc, sv.z, v2);
            FMA4(acc, sv.w, v3);
        }
        *(float4*)(y + base + (size_t)(ch * 64 + cw) * DMODEL + dd) = acc;

        // M[cw][dd..] += sum_c k[c][cw] * v[c][dd..]   (k[c][cw] = kTs[cw][c])
        // (Ms writes ordered after all y1 Ms-reads by the two syncs above)
        float4 mac = *(const float4*)(Ms + cw * 64 + dd);
#pragma unroll
        for (int c0 = 0; c0 < 64; c0 += 4) {
            const float4 kv = *(const float4*)(kTs + cw * 64 + c0);
            const float4 v0 = *(const float4*)(vs + (c0 + 0) * 64 + dd);
            const float4 v1 = *(const float4*)(vs + (c0 + 1) * 64 + dd);
            const float4 v2 = *(const float4*)(vs + (c0 + 2) * 64 + dd);
            const float4 v3 = *(const float4*)(vs + (c0 + 3) * 64 + dd);
            FMA4(mac, kv.x, v0);
            FMA4(mac, kv.y, v1);
            FMA4(mac, kv.z, v2);
            FMA4(mac, kv.w, v3);
        }
        *(float4*)(Ms + cw * 64 + dd) = mac;
    }
}

// ---------------- launch -------------------------------------------------------
extern "C" void kernel_launch(void* const* d_in, const int* in_sizes, int n_in,
                              void* d_out, int out_size, void* d_ws, size_t ws_size,
                              hipStream_t stream)
{
    const float* x      = (const float*)d_in[0];
    const float* norm_w = (const float*)d_in[1];
    const float* w_up   = (const float*)d_in[2];
    const float* w_gate = (const float*)d_in[3];
    const float* w_down = (const float*)d_in[4];
    const float* conv_w = (const float*)d_in[5];
    const float* conv_b = (const float*)d_in[6];
    const float* wq     = (const float*)d_in[7];
    const float* wk     = (const float*)d_in[8];
    const float* wv     = (const float*)d_in[9];
    const float* wo     = (const float*)d_in[10];

    float* ws  = (float*)d_ws;
    float* out = (float*)d_out;

    const bool big = ws_size >= (size_t)268435456;  // 256 MiB: up+gate fully resident

    if (big) {
        // ws layout (floats), exactly 256 MiB:
        //   phase A: up [0, 33.55M)  gate [33.55M, 67.11M)
        //   phase B: q [0, 16.78M)  k [16.78M, 33.55M)  v [33.55M, 50.33M)  y [50.33M, 67.11M)
        // scale lives in d_out head (needed only before down-GEMM overwrites d_out with h).
        float* scaleb = out;               // 16384 floats, overwritten by h later
        float* upb    = ws;
        float* gateb  = ws + (size_t)NR * DINNER;
        float* qb     = ws;
        float* kb     = ws + (size_t)NR * DMODEL;
        float* vb     = ws + 2 * (size_t)NR * DMODEL;
        float* yb     = ws + 3 * (size_t)NR * DMODEL;
        float* hb     = out;

        rms_scale_k<<<NR, 256, 0, stream>>>(x, scaleb);

        dim3 gUP(DINNER / 128, NR / 128);
        gemm_k<0><<<gUP, 256, 0, stream>>>(x, w_up,   upb,   NR, DINNER, DMODEL, scaleb, norm_w, nullptr);
        gemm_k<0><<<gUP, 256, 0, stream>>>(x, w_gate, gateb, NR, DINNER, DMODEL, scaleb, norm_w, nullptr);

        conv_gate_k<<<(NR * (DINNER / 4)) / 256, 256, 0, stream>>>(upb, gateb, conv_w, conv_b);

        dim3 gD(DMODEL / 128, NR / 128);
        gemm_k<0><<<gD, 256, 0, stream>>>(gateb, w_down, hb, NR, DMODEL, DINNER, nullptr, nullptr, nullptr);

        gemm_k<1><<<gD, 256, 0, stream>>>(hb, wq, qb, NR, DMODEL, DMODEL, nullptr, nullptr, nullptr);
        gemm_k<2><<<gD, 256, 0, stream>>>(hb, wk, kb, NR, DMODEL, DMODEL, nullptr, nullptr, nullptr);
        gemm_k<0><<<gD, 256, 0, stream>>>(hb, wv, vb, NR, DMODEL, DMODEL, nullptr, nullptr, nullptr);

        hebbian_scan_k<<<64, 1024, 0, stream>>>(qb, kb, vb, yb);

        gemm_k<3><<<gD, 256, 0, stream>>>(yb, wo, out, NR, DMODEL, DMODEL, nullptr, nullptr, x);
    } else {
        // per-batch chunked path, ws requirement = 64KB + 67.1MB.
        // ws: scale [0,16384) | blk [16384, 16384+16.78M)
        //   per batch: up=blk[0,8.39M) gate=blk[8.39M,16.78M)
        //   then:      q=blk[0,4.19M) k=blk[4.19M,8.39M) v=blk[8.39M,12.58M), y aliases k
        float* scaleb = ws;
        float* blk    = ws + 16384;
        const size_t RB = (size_t)SEQ;            // 4096 rows per batch

        rms_scale_k<<<NR, 256, 0, stream>>>(x, scaleb);

        for (int b = 0; b < 4; ++b) {
            const float* xb = x + (size_t)b * RB * DMODEL;
            float* hb  = out + (size_t)b * RB * DMODEL;
            float* upb   = blk;
            float* gateb = blk + RB * DINNER;
            float* qb    = blk;
            float* kb    = blk + RB * DMODEL;
            float* vb    = blk + 2 * RB * DMODEL;
            float* yb    = kb;                    // alias (safe, see scan kernel note)

            dim3 gUP(DINNER / 128, SEQ / 128);
            gemm_k<0><<<gUP, 256, 0, stream>>>(xb, w_up,   upb,   SEQ, DINNER, DMODEL, scaleb + b * SEQ, norm_w, nullptr);
            gemm_k<0><<<gUP, 256, 0, stream>>>(xb, w_gate, gateb, SEQ, DINNER, DMODEL, scaleb + b * SEQ, norm_w, nullptr);

            conv_gate_k<<<(SEQ * (DINNER / 4)) / 256, 256, 0, stream>>>(upb, gateb, conv_w, conv_b);

            dim3 gD(DMODEL / 128, SEQ / 128);
            gemm_k<0><<<gD, 256, 0, stream>>>(gateb, w_down, hb, SEQ, DMODEL, DINNER, nullptr, nullptr, nullptr);

            gemm_k<1><<<gD, 256, 0, stream>>>(hb, wq, qb, SEQ, DMODEL, DMODEL, nullptr, nullptr, nullptr);
            gemm_k<2><<<gD, 256, 0, stream>>>(hb, wk, kb, SEQ, DMODEL, DMODEL, nullptr, nullptr, nullptr);
            gemm_k<0><<<gD, 256, 0, stream>>>(hb, wv, vb, SEQ, DMODEL, DMODEL, nullptr, nullptr, nullptr);

            hebbian_scan_k<<<16, 1024, 0, stream>>>(qb, kb, vb, yb);

            gemm_k<3><<<gD, 256, 0, stream>>>(yb, wo, hb, SEQ, DMODEL, DMODEL, nullptr, nullptr, xb);
        }
    }
}

// Round 3
// 2599.090 us; speedup vs baseline: 2.1782x; 2.1782x over previous
//
#include <hip/hip_runtime.h>
#include <hip/hip_bf16.h>
#include <cstdint>

// Problem constants (B=4, S=4096, D=1024)
#define NR      16384   // B*S rows
#define DMODEL  1024
#define DINNER  2048
#define SEQ     4096

typedef __attribute__((ext_vector_type(8))) short s8v;   // 8 bf16 (4 VGPR)
typedef __attribute__((ext_vector_type(4))) float f4v;   // MFMA acc

__device__ __forceinline__ float phi_f(float t)  { return t > 0.0f ? t + 1.0f : __expf(t); }
__device__ __forceinline__ float silu_f(float t) { return t / (1.0f + __expf(-t)); }

__device__ __forceinline__ unsigned short f2bf_rne(float x) {
    unsigned u = __float_as_uint(x);
    return (unsigned short)((u + 0x7fffu + ((u >> 16) & 1u)) >> 16);
}
__device__ __forceinline__ float bf2f(unsigned short h) {
    return __uint_as_float(((unsigned)h) << 16);
}

// ---------------- 1. per-row RMS scale -----------------------------------------
__global__ __launch_bounds__(256) void rms_scale_k(const float* __restrict__ x,
                                                   float* __restrict__ scale)
{
    const int r = blockIdx.x;
    const float4 v = *(const float4*)(x + (size_t)r * DMODEL + threadIdx.x * 4);
    float s = v.x * v.x + v.y * v.y + v.z * v.z + v.w * v.w;
#pragma unroll
    for (int m = 1; m < 64; m <<= 1) s += __shfl_xor(s, m);
    __shared__ float wsum[4];
    const int lane = threadIdx.x & 63, w = threadIdx.x >> 6;
    if (lane == 0) wsum[w] = s;
    __syncthreads();
    if (threadIdx.x == 0) {
        const float tot = wsum[0] + wsum[1] + wsum[2] + wsum[3];
        scale[r] = rsqrtf(tot * (1.0f / DMODEL) + 1e-5f);
    }
}

// ---------------- 2. weight pre-format: W[K][N] fp32 -> hi/lo bf16 cells -------
// Cell (kb, n): 32 bytes = [16B: 8 bf16 hi of k=8kb..8kb+7][16B: lo], halves
// swapped when ((n>>2)&1)==1 (bank-swizzle for the GEMM's ds_read_b128).
__global__ __launch_bounds__(256) void wfmt_k(const float* __restrict__ W,
                                              char* __restrict__ out,
                                              int K, int N)
{
    __shared__ float tile[64][65];
    const int t = threadIdx.x;
    const int n0 = blockIdx.x * 64, k0 = blockIdx.y * 64;
#pragma unroll
    for (int i = 0; i < 4; ++i) {
        const int r = (t >> 4) + i * 16;
        const int c4 = (t & 15) * 4;
        *(float4*)&tile[r][c4] = *(const float4*)(W + (size_t)(k0 + r) * N + n0 + c4);
    }
    __syncthreads();
#pragma unroll
    for (int s = 0; s < 2; ++s) {
        const int id = t + 256 * s;      // 0..511
        const int kbl = id >> 6;         // 0..7
        const int n = id & 63;
        unsigned hw[4], lw[4];
#pragma unroll
        for (int p = 0; p < 4; ++p) {
            const float x0 = tile[kbl * 8 + 2 * p][n];
            const float x1 = tile[kbl * 8 + 2 * p + 1][n];
            const unsigned short h0 = f2bf_rne(x0), h1 = f2bf_rne(x1);
            const unsigned short l0 = f2bf_rne(x0 - bf2f(h0));
            const unsigned short l1 = f2bf_rne(x1 - bf2f(h1));
            hw[p] = (unsigned)h0 | ((unsigned)h1 << 16);
            lw[p] = (unsigned)l0 | ((unsigned)l1 << 16);
        }
        char* o = out + ((size_t)(k0 / 8 + kbl) * N + (n0 + n)) * 32;
        const int pe = ((n0 + n) >> 2) & 1;
        *(uint4*)(o + pe * 16)       = make_uint4(hw[0], hw[1], hw[2], hw[3]);
        *(uint4*)(o + (1 - pe) * 16) = make_uint4(lw[0], lw[1], lw[2], lw[3]);
    }
}

// ---------------- 3. split-bf16 MFMA GEMM, 128x128 tile, BK=32 -----------------
// C = A*B with A fp32 (optionally rmsnorm-fused) and B pre-formatted hi/lo.
// 3-term split: Ah*Bh + Ah*Bl + Al*Bh  (fp32-grade accuracy).
// EPI: 0 none, 1 phi(t)*0.125, 2 phi(t), 3 +addx.
template <int EPI>
__global__ __launch_bounds__(256, 2) void mgemm_k(const float* __restrict__ A,
                                                  const char* __restrict__ Bfmt,
                                                  float* __restrict__ C,
                                                  int M, int N, int K,
                                                  const float* __restrict__ rowscale,
                                                  const float* __restrict__ normw,
                                                  const float* __restrict__ addx)
{
    __shared__ char As[16384];   // [m 0..127][slot 0..7][16B], slot=(2kb+p)^(m&7)
    __shared__ char Bs[16384];   // [kb 0..3][n 0..127][32B cell], halves pre-swizzled

    const int t = threadIdx.x;
    const int bm = blockIdx.y * 128, bn = blockIdx.x * 128;
    const int lane = t & 63;
    const int wv = t >> 6;
    const int wm = wv >> 1, wn = wv & 1;

    const int am = t >> 3;        // A staging row (+32*i)
    const int ak4 = t & 7;        // A staging float4-col

    float rs[4];
#pragma unroll
    for (int i = 0; i < 4; ++i)
        rs[i] = rowscale ? rowscale[bm + am + 32 * i] : 1.0f;

    const float* Ap = A + (size_t)(bm + am) * K + ak4 * 4;

    f4v acc[4][4];
#pragma unroll
    for (int i = 0; i < 4; ++i)
#pragma unroll
        for (int j = 0; j < 4; ++j) acc[i][j] = (f4v)0.0f;

    float4 pa[4];
    uint4  pb[4];
    float4 pnw = make_float4(1.f, 1.f, 1.f, 1.f);

    const int NT = K / 32;

    // prefetch tile 0
#pragma unroll
    for (int i = 0; i < 4; ++i)
        pa[i] = *(const float4*)(Ap + (size_t)(32 * i) * K);
    if (normw) pnw = *(const float4*)(normw + ak4 * 4);
    {
        const char* gb = Bfmt + ((size_t)0 * N + bn) * 32;
#pragma unroll
        for (int i = 0; i < 4; ++i) {
            const int id = t + 256 * i, kbl = id >> 8, c = id & 255;
            pb[i] = *(const uint4*)(gb + (size_t)kbl * N * 32 + c * 16);
        }
    }

    for (int kt = 0; kt < NT; ++kt) {
        __syncthreads();
        // ---- stage LDS from prefetched regs
#pragma unroll
        for (int i = 0; i < 4; ++i) {
            const int id = t + 256 * i;
            *(uint4*)(Bs + id * 16) = pb[i];
        }
#pragma unroll
        for (int i = 0; i < 4; ++i) {
            const int m = am + 32 * i;
            float4 w = pa[i];
            if (rowscale) {
                const float s = rs[i];
                w.x *= s * pnw.x; w.y *= s * pnw.y; w.z *= s * pnw.z; w.w *= s * pnw.w;
            }
            const unsigned short h0 = f2bf_rne(w.x), h1 = f2bf_rne(w.y),
                                 h2 = f2bf_rne(w.z), h3 = f2bf_rne(w.w);
            const unsigned short l0 = f2bf_rne(w.x - bf2f(h0)), l1 = f2bf_rne(w.y - bf2f(h1)),
                                 l2 = f2bf_rne(w.z - bf2f(h2)), l3 = f2bf_rne(w.w - bf2f(h3));
            const uint2 hv = make_uint2((unsigned)h0 | ((unsigned)h1 << 16),
                                        (unsigned)h2 | ((unsigned)h3 << 16));
            const uint2 lv = make_uint2((unsigned)l0 | ((unsigned)l1 << 16),
                                        (unsigned)l2 | ((unsigned)l3 << 16));
            const int kb = ak4 >> 1, half8 = (ak4 & 1) * 8;
            const int sh = (2 * kb + 0) ^ (m & 7);
            const int sl = (2 * kb + 1) ^ (m & 7);
            *(uint2*)(As + m * 128 + sh * 16 + half8) = hv;
            *(uint2*)(As + m * 128 + sl * 16 + half8) = lv;
        }
        // ---- prefetch next tile (overlaps with compute below)
        if (kt + 1 < NT) {
            const int k0 = (kt + 1) * 32;
#pragma unroll
            for (int i = 0; i < 4; ++i)
                pa[i] = *(const float4*)(Ap + (size_t)(32 * i) * K + k0);
            if (normw) pnw = *(const float4*)(normw + k0 + ak4 * 4);
            const char* gb = Bfmt + ((size_t)(k0 >> 3) * N + bn) * 32;
#pragma unroll
            for (int i = 0; i < 4; ++i) {
                const int id = t + 256 * i, kbl = id >> 8, c = id & 255;
                pb[i] = *(const uint4*)(gb + (size_t)kbl * N * 32 + c * 16);
            }
        }
        __syncthreads();
        // ---- compute
        const int kb = lane >> 4;
        const int lr = lane & 15;
        s8v ah[4], al[4];
#pragma unroll
        for (int fm = 0; fm < 4; ++fm) {
            const int m = wm * 64 + fm * 16 + lr;
            const int s0 = (2 * kb + 0) ^ (m & 7);
            const int s1 = (2 * kb + 1) ^ (m & 7);
            ah[fm] = *(const s8v*)(As + m * 128 + s0 * 16);
            al[fm] = *(const s8v*)(As + m * 128 + s1 * 16);
        }
#pragma unroll
        for (int fn = 0; fn < 4; ++fn) {
            const int n = wn * 64 + fn * 16 + lr;
            const int pe = (n >> 2) & 1;
            const s8v bh = *(const s8v*)(Bs + kb * 4096 + n * 32 + (0 ^ pe) * 16);
            const s8v bl = *(const s8v*)(Bs + kb * 4096 + n * 32 + (1 ^ pe) * 16);
#pragma unroll
            for (int fm = 0; fm < 4; ++fm) {
                acc[fm][fn] = __builtin_amdgcn_mfma_f32_16x16x32_bf16(ah[fm], bh, acc[fm][fn], 0, 0, 0);
                acc[fm][fn] = __builtin_amdgcn_mfma_f32_16x16x32_bf16(ah[fm], bl, acc[fm][fn], 0, 0, 0);
                acc[fm][fn] = __builtin_amdgcn_mfma_f32_16x16x32_bf16(al[fm], bh, acc[fm][fn], 0, 0, 0);
            }
        }
    }

    // ---- epilogue
#pragma unroll
    for (int fm = 0; fm < 4; ++fm) {
        const int row0 = bm + wm * 64 + fm * 16 + ((lane >> 4) << 2);
#pragma unroll
        for (int fn = 0; fn < 4; ++fn) {
            const int col = bn + wn * 64 + fn * 16 + (lane & 15);
#pragma unroll
            for (int r = 0; r < 4; ++r) {
                float o = acc[fm][fn][r];
                if (EPI == 1) o = phi_f(o) * 0.125f;
                else if (EPI == 2) o = phi_f(o);
                else if (EPI == 3) o += addx[(size_t)(row0 + r) * N + col];
                C[(size_t)(row0 + r) * N + col] = o;
            }
        }
    }
}

// ---------------- 4. causal depthwise conv + silu + gate (in-place) ------------
__global__ __launch_bounds__(256) void conv_gate_k(const float* __restrict__ up,
                                                   float* __restrict__ gate,
                                                   const float* __restrict__ cw,
                                                   const float* __restrict__ cb)
{
    const int idx = blockIdx.x * 256 + threadIdx.x;  // float4 index
    const int row = idx >> 9;
    const int s   = row & (SEQ - 1);
    const int c   = (idx & 511) * 4;

    const float4 t0 = *(const float4*)(cw + (size_t)(c + 0) * 4);
    const float4 t1 = *(const float4*)(cw + (size_t)(c + 1) * 4);
    const float4 t2 = *(const float4*)(cw + (size_t)(c + 2) * 4);
    const float4 t3 = *(const float4*)(cw + (size_t)(c + 3) * 4);
    const float ta0[4] = {t0.x, t0.y, t0.z, t0.w};
    const float ta1[4] = {t1.x, t1.y, t1.z, t1.w};
    const float ta2[4] = {t2.x, t2.y, t2.z, t2.w};
    const float ta3[4] = {t3.x, t3.y, t3.z, t3.w};

    float4 acc = *(const float4*)(cb + c);
#pragma unroll
    for (int j = 0; j < 4; ++j) {
        const int sj = s - 3 + j;
        if (sj >= 0) {
            const float4 u = *(const float4*)(up + ((size_t)row - 3 + j) * DINNER + c);
            acc.x = fmaf(u.x, ta0[j], acc.x);
            acc.y = fmaf(u.y, ta1[j], acc.y);
            acc.z = fmaf(u.z, ta2[j], acc.z);
            acc.w = fmaf(u.w, ta3[j], acc.w);
        }
    }
    float4 gv = *(const float4*)(gate + (size_t)idx * 4);
    float4 o;
    o.x = silu_f(gv.x) * silu_f(acc.x);
    o.y = silu_f(gv.y) * silu_f(acc.y);
    o.z = silu_f(gv.z) * silu_f(acc.z);
    o.w = silu_f(gv.w) * silu_f(acc.w);
    *(float4*)(gate + (size_t)idx * 4) = o;
}

// ---------------- 5a. per-chunk Hebbian outer products: G[h][ch] = K^T V -------
__global__ __launch_bounds__(256) void gscan_g_k(const float* __restrict__ kk,
                                                 const float* __restrict__ v,
                                                 float* __restrict__ G)
{
    __shared__ float Ks[64 * 64];
    __shared__ float Vs[64 * 64];
    const int t = threadIdx.x;
    const int ch = blockIdx.x, h = blockIdx.y;
    const int r = t >> 2, c16 = (t & 3) * 16;
    const size_t gbase = (size_t)(ch * 64 + r) * DMODEL + h * 64 + c16;
#pragma unroll
    for (int i = 0; i < 4; ++i) {
        *(float4*)(Ks + r * 64 + c16 + 4 * i) = *(const float4*)(kk + gbase + 4 * i);
        *(float4*)(Vs + r * 64 + c16 + 4 * i) = *(const float4*)(v + gbase + 4 * i);
    }
    __syncthreads();
    const int d4 = (t >> 4) * 4, e4 = (t & 15) * 4;
    float accg[4][4] = {};
#pragma unroll 4
    for (int c = 0; c < 64; ++c) {
        float ka[4], va[4];
        *(float4*)ka = *(const float4*)(Ks + c * 64 + d4);
        *(float4*)va = *(const float4*)(Vs + c * 64 + e4);
#pragma unroll
        for (int i = 0; i < 4; ++i)
#pragma unroll
            for (int j = 0; j < 4; ++j)
                accg[i][j] = fmaf(ka[i], va[j], accg[i][j]);
    }
    float* go = G + (size_t)(h * 64 + ch) * 4096 + d4 * 64 + e4;
#pragma unroll
    for (int i = 0; i < 4; ++i)
        *(float4*)(go + i * 64) = make_float4(accg[i][0], accg[i][1], accg[i][2], accg[i][3]);
}

// ---------------- 5b. in-place exclusive prefix over chunks --------------------
// G[h][ch] := sum_{c<ch} G[h][c]
__global__ __launch_bounds__(256) void gscan_prefix_k(float* __restrict__ G)
{
    const int t = threadIdx.x;
    const int h = blockIdx.x >> 2, sl = blockIdx.x & 3;
    const int d = t >> 2, e4 = sl * 16 + (t & 3) * 4;
    float4 run = make_float4(0.f, 0.f, 0.f, 0.f);
    float* p = G + (size_t)(h * 64) * 4096 + d * 64 + e4;
#pragma unroll 2
    for (int ch = 0; ch < 64; ++ch) {
        const float4 g = *(const float4*)p;
        *(float4*)p = run;
        run.x += g.x; run.y += g.y; run.z += g.z; run.w += g.w;
        p += 4096;
    }
}

// ---------------- 5c. per-chunk read: y = q*M_excl + tril(q k^T) v -------------
// y may alias kk: block (ch,h) reads only its own (ch,h) K-slice before writing
// the same (ch,h) y-slice; no other block touches that region.
__global__ __launch_bounds__(256) void gscan_y_k(const float* __restrict__ q,
                                                 const float* __restrict__ kk,
                                                 const float* __restrict__ v,
                                                 const float* __restrict__ M,
                                                 float* __restrict__ y)
{
    __shared__ float qT[64 * 64];   // qT[d][c]; later scT[e][c]
    __shared__ float Kd[64 * 64];   // Kd[d][e] = K[e][d]
    __shared__ float Vs[64 * 64];   // V[c][j]
    __shared__ float Ms[64 * 64];   // M[d][j]
    const int t = threadIdx.x;
    const int ch = blockIdx.x, h = blockIdx.y;
    const int r = t >> 2, c16 = (t & 3) * 16;
    const size_t gbase = (size_t)(ch * 64 + r) * DMODEL + h * 64 + c16;
#pragma unroll
    for (int i = 0; i < 4; ++i) {
        const float4 qv = *(const float4*)(q + gbase + 4 * i);
        const float4 kv = *(const float4*)(kk + gbase + 4 * i);
        qT[(c16 + 4 * i + 0) * 64 + r] = qv.x;
        qT[(c16 + 4 * i + 1) * 64 + r] = qv.y;
        qT[(c16 + 4 * i + 2) * 64 + r] = qv.z;
        qT[(c16 + 4 * i + 3) * 64 + r] = qv.w;
        Kd[(c16 + 4 * i + 0) * 64 + r] = kv.x;
        Kd[(c16 + 4 * i + 1) * 64 + r] = kv.y;
        Kd[(c16 + 4 * i + 2) * 64 + r] = kv.z;
        Kd[(c16 + 4 * i + 3) * 64 + r] = kv.w;
        *(float4*)(Vs + r * 64 + c16 + 4 * i) = *(const float4*)(v + gbase + 4 * i);
    }
    const float* mg = M + (size_t)(h * 64 + ch) * 4096;
#pragma unroll
    for (int i = 0; i < 4; ++i)
        *(float4*)(Ms + t * 16 + 4 * i) = *(const float4*)(mg + t * 16 + 4 * i);
    __syncthreads();

    const int c4 = (t >> 4) * 4, e4 = (t & 15) * 4;
    float sa[4][4] = {}, ya[4][4] = {};
#pragma unroll 2
    for (int d = 0; d < 64; ++d) {
        float a[4], b[4], m[4];
        *(float4*)a = *(const float4*)(qT + d * 64 + c4);
        *(float4*)b = *(const float4*)(Kd + d * 64 + e4);
        *(float4*)m = *(const float4*)(Ms + d * 64 + e4);
#pragma unroll
        for (int i = 0; i < 4; ++i)
#pragma unroll
            for (int j = 0; j < 4; ++j) {
                sa[i][j] = fmaf(a[i], b[j], sa[i][j]);
                ya[i][j] = fmaf(a[i], m[j], ya[i][j]);
            }
    }
#pragma unroll
    for (int i = 0; i < 4; ++i)
#pragma unroll
        for (int j = 0; j < 4; ++j)
            if (e4 + j > c4 + i) sa[i][j] = 0.0f;
    __syncthreads();
#pragma unroll
    for (int i = 0; i < 4; ++i)
#pragma unroll
        for (int j = 0; j < 4; ++j)
            qT[(e4 + j) * 64 + c4 + i] = sa[i][j];   // scT[e][c]
    __syncthreads();
#pragma unroll 2
    for (int e = 0; e < 64; ++e) {
        float a[4], vv[4];
        *(float4*)a = *(const float4*)(qT + e * 64 + c4);
        *(float4*)vv = *(const float4*)(Vs + e * 64 + e4);
#pragma unroll
        for (int i = 0; i < 4; ++i)
#pragma unroll
            for (int j = 0; j < 4; ++j)
                ya[i][j] = fmaf(a[i], vv[j], ya[i][j]);
    }
    float* yo = y + (size_t)(ch * 64 + c4) * DMODEL + h * 64 + e4;
#pragma unroll
    for (int i = 0; i < 4; ++i)
        *(float4*)(yo + (size_t)i * DMODEL) = make_float4(ya[i][0], ya[i][1], ya[i][2], ya[i][3]);
}

// ---------------- launch -------------------------------------------------------
// ws layout (bytes), total ~120.1 MB:
//   [0, 64K)            rms row scales (NR floats)
//   [64K, +8M)          fmt w_up      [+8M) fmt w_gate   [+8M) fmt w_down
//   [.., +4M x4)        fmt wq, wk, wv, wo
//   actA 32MB           per-batch up   -> later q | k (y aliases k)
//   actB 32MB           per-batch gate -> later v
//   G    16.8MB         per-batch Hebbian prefix states
extern "C" void kernel_launch(void* const* d_in, const int* in_sizes, int n_in,
                              void* d_out, int out_size, void* d_ws, size_t ws_size,
                              hipStream_t stream)
{
    const float* x      = (const float*)d_in[0];
    const float* norm_w = (const float*)d_in[1];
    const float* w_up   = (const float*)d_in[2];
    const float* w_gate = (const float*)d_in[3];
    const float* w_down = (const float*)d_in[4];
    const float* conv_w = (const float*)d_in[5];
    const float* conv_b = (const float*)d_in[6];
    const float* wq     = (const float*)d_in[7];
    const float* wk     = (const float*)d_in[8];
    const float* wv     = (const float*)d_in[9];
    const float* wo     = (const float*)d_in[10];

    char* wsb = (char*)d_ws;
    float* out = (float*)d_out;

    float* scaleb = (float*)wsb;
    char* fup   = wsb + 65536;
    char* fgate = fup   + (size_t)8  * 1024 * 1024;
    char* fdown = fgate + (size_t)8  * 1024 * 1024;
    char* fq    = fdown + (size_t)8  * 1024 * 1024;
    char* fk    = fq    + (size_t)4  * 1024 * 1024;
    char* fv    = fk    + (size_t)4  * 1024 * 1024;
    char* fo    = fv    + (size_t)4  * 1024 * 1024;
    float* actA = (float*)(fo + (size_t)4 * 1024 * 1024);
    float* actB = actA + (size_t)SEQ * DINNER;
    float* Gbuf = actB + (size_t)SEQ * DINNER;

    rms_scale_k<<<NR, 256, 0, stream>>>(x, scaleb);

    wfmt_k<<<dim3(DINNER / 64, DMODEL / 64), 256, 0, stream>>>(w_up,   fup,   DMODEL, DINNER);
    wfmt_k<<<dim3(DINNER / 64, DMODEL / 64), 256, 0, stream>>>(w_gate, fgate, DMODEL, DINNER);
    wfmt_k<<<dim3(DMODEL / 64, DINNER / 64), 256, 0, stream>>>(w_down, fdown, DINNER, DMODEL);
    wfmt_k<<<dim3(DMODEL / 64, DMODEL / 64), 256, 0, stream>>>(wq, fq, DMODEL, DMODEL);
    wfmt_k<<<dim3(DMODEL / 64, DMODEL / 64), 256, 0, stream>>>(wk, fk, DMODEL, DMODEL);
    wfmt_k<<<dim3(DMODEL / 64, DMODEL / 64), 256, 0, stream>>>(wv, fv, DMODEL, DMODEL);
    wfmt_k<<<dim3(DMODEL / 64, DMODEL / 64), 256, 0, stream>>>(wo, fo, DMODEL, DMODEL);

    const dim3 gUP(DINNER / 128, SEQ / 128);   // (16, 32)
    const dim3 gD(DMODEL / 128, SEQ / 128);    // (8, 32)
    const dim3 gS(64, 16);                     // (chunk, head)

    for (int b = 0; b < 4; ++b) {
        const float* xb = x + (size_t)b * SEQ * DMODEL;
        float* hb = out + (size_t)b * SEQ * DMODEL;
        float* upb   = actA;
        float* gateb = actB;
        float* qb2 = actA;
        float* kb2 = actA + (size_t)SEQ * DMODEL;
        float* vb2 = actB;
        float* yb2 = kb2;   // alias, safe (see gscan_y_k)

        mgemm_k<0><<<gUP, 256, 0, stream>>>(xb, fup,   upb,   SEQ, DINNER, DMODEL, scaleb + b * SEQ, norm_w, nullptr);
        mgemm_k<0><<<gUP, 256, 0, stream>>>(xb, fgate, gateb, SEQ, DINNER, DMODEL, scaleb + b * SEQ, norm_w, nullptr);

        conv_gate_k<<<(SEQ * (DINNER / 4)) / 256, 256, 0, stream>>>(upb, gateb, conv_w, conv_b);

        mgemm_k<0><<<gD, 256, 0, stream>>>(gateb, fdown, hb, SEQ, DMODEL, DINNER, nullptr, nullptr, nullptr);

        mgemm_k<1><<<gD, 256, 0, stream>>>(hb, fq, qb2, SEQ, DMODEL, DMODEL, nullptr, nullptr, nullptr);
        mgemm_k<2><<<gD, 256, 0, stream>>>(hb, fk, kb2, SEQ, DMODEL, DMODEL, nullptr, nullptr, nullptr);
        mgemm_k<0><<<gD, 256, 0, stream>>>(hb, fv, vb2, SEQ, DMODEL, DMODEL, nullptr, nullptr, nullptr);

        gscan_g_k<<<gS, 256, 0, stream>>>(kb2, vb2, Gbuf);
        gscan_prefix_k<<<64, 256, 0, stream>>>(Gbuf);
        gscan_y_k<<<gS, 256, 0, stream>>>(qb2, kb2, vb2, Gbuf, yb2);

        mgemm_k<3><<<gD, 256, 0, stream>>>(yb2, fo, hb, SEQ, DMODEL, DMODEL, nullptr, nullptr, xb);
    }
}

// Round 4
// 857.098 us; speedup vs baseline: 6.6053x; 3.0324x over previous
//
#include <hip/hip_runtime.h>
#include <hip/hip_fp16.h>
#include <cstdint>

// Problem constants (B=4, S=4096, D=1024)
#define NRALL 16384
#define DM    1024
#define DI    2048
#define SEQL  4096

typedef _Float16 f16;
typedef _Float16 f16x8 __attribute__((ext_vector_type(8)));
typedef _Float16 f16x4 __attribute__((ext_vector_type(4)));
typedef float    f32x4 __attribute__((ext_vector_type(4)));

__device__ __forceinline__ float phi_f(float t)  { return t > 0.0f ? t + 1.0f : __expf(t); }
__device__ __forceinline__ float silu_f(float t) { return t / (1.0f + __expf(-t)); }

#define GLDS16(g, l)                                                            \
    __builtin_amdgcn_global_load_lds(                                           \
        (const __attribute__((address_space(1))) void*)(g),                     \
        (__attribute__((address_space(3))) void*)(l), 16, 0, 0)

#define FMA4(dst, s, vv)                      \
    dst.x = fmaf((s), (vv).x, dst.x);         \
    dst.y = fmaf((s), (vv).y, dst.y);         \
    dst.z = fmaf((s), (vv).z, dst.z);         \
    dst.w = fmaf((s), (vv).w, dst.w);

// ---------------- 1. rmsnorm: xn[r][c] = f16(x[r][c] * rsqrt(mean x^2 + eps) * nw[c])
__global__ __launch_bounds__(256) void rmsnorm_k(const float* __restrict__ x,
                                                 const float* __restrict__ nw,
                                                 f16* __restrict__ xn)
{
    const int r = blockIdx.x, t = threadIdx.x;
    const float4 v = *(const float4*)(x + (size_t)r * DM + t * 4);
    float s = v.x * v.x + v.y * v.y + v.z * v.z + v.w * v.w;
#pragma unroll
    for (int m = 1; m < 64; m <<= 1) s += __shfl_xor(s, m);
    __shared__ float ws4[4];
    if ((t & 63) == 0) ws4[t >> 6] = s;
    __syncthreads();
    const float tot = ws4[0] + ws4[1] + ws4[2] + ws4[3];
    const float sc = rsqrtf(tot * (1.0f / DM) + 1e-5f);
    const float4 w = *(const float4*)(nw + t * 4);
    f16x4 o;
    o[0] = (f16)(v.x * sc * w.x); o[1] = (f16)(v.y * sc * w.y);
    o[2] = (f16)(v.z * sc * w.z); o[3] = (f16)(v.w * sc * w.w);
    *(f16x4*)(xn + (size_t)r * DM + t * 4) = o;
}

// ---------------- 2. weight format: W[K][Nw] fp32 -> fmt cells ------------------
// fmt[(kt*Ntot + ng)*64 + slot*16] holds 8 f16 of k = kt*32 + (slot^((ng>>1)&3))*8 ..+7
__global__ __launch_bounds__(256) void wfmt_k(const float* __restrict__ W,
                                              char* __restrict__ fmt,
                                              int Nw, int Ntot, int noff)
{
    const int n  = blockIdx.x * 256 + threadIdx.x;
    const int kt = blockIdx.y;
    const int ng = noff + n;
    char* o = fmt + ((size_t)kt * Ntot + ng) * 64;
#pragma unroll
    for (int c = 0; c < 4; ++c) {
        f16x8 p;
#pragma unroll
        for (int j = 0; j < 8; ++j)
            p[j] = (f16)W[(size_t)(kt * 32 + c * 8 + j) * Nw + n];
        *(f16x8*)(o + ((c ^ ((ng >> 1) & 3)) << 4)) = p;
    }
}

// ---------------- 3. f16 MFMA GEMM, 128xBN tile, BK=32, dbuf glds staging -------
// EPI: 0 -> f16 out; 1 -> qkv fused epilogue (phi*0.125 | phi | id by col range), f16 out;
//      2 -> +addx, fp32 out.
template <int BN, int EPI>
__global__ __launch_bounds__(256, 4) void mgemm16_k(const f16* __restrict__ A, int lda,
                                                    const char* __restrict__ fmt,
                                                    void* __restrict__ Cv,
                                                    int N, int K, int gy,
                                                    const float* __restrict__ addx)
{
    constexpr int FN = BN / 32;
    constexpr int BROUNDS = (BN * 64) / 4096;
    __shared__ char lds[BN == 128 ? 32768 : 24576];
    char* As = lds;            // 2 x 8KB
    char* Bs = lds + 16384;    // 2 x BN*64

    const int t = threadIdx.x;
    int wid = blockIdx.x;
    { const int cpx = gridDim.x >> 3; wid = (wid & 7) * cpx + (wid >> 3); }  // XCD swizzle
    const int bx = wid / gy, by = wid % gy;
    const int bm = by * 128, bn = bx * BN;
    const int lane = t & 63, wv = t >> 6;
    const int wm = wv >> 1, wn = wv & 1;
    const int kb = lane >> 4, lr = lane & 15;
    const int NT = K >> 5;

    f32x4 acc[4][FN];
#pragma unroll
    for (int i = 0; i < 4; ++i)
#pragma unroll
        for (int j = 0; j < FN; ++j) acc[i][j] = (f32x4)0.0f;

    auto STAGE = [&](int buf, int kt) {
#pragma unroll
        for (int r = 0; r < 2; ++r) {
            const int id = t + 256 * r;
            const int row = id >> 2, sl = id & 3;
            const f16* src = A + (size_t)(bm + row) * lda + kt * 32 + ((sl ^ ((row >> 1) & 3)) << 3);
            GLDS16(src, As + buf * 8192 + ((wv * 64 + 256 * r) << 4));
        }
#pragma unroll
        for (int r = 0; r < BROUNDS; ++r) {
            const char* src = fmt + ((size_t)kt * N + bn) * 64 + (size_t)(t + 256 * r) * 16;
            GLDS16(src, Bs + buf * (BN * 64) + ((wv * 64 + 256 * r) << 4));
        }
    };

    STAGE(0, 0);
    __syncthreads();
    int buf = 0;
    for (int kt = 0; kt < NT; ++kt) {
        if (kt + 1 < NT) STAGE(buf ^ 1, kt + 1);
        f16x8 af[4];
#pragma unroll
        for (int fm = 0; fm < 4; ++fm) {
            const int row = wm * 64 + fm * 16 + lr;
            af[fm] = *(const f16x8*)(As + buf * 8192 + row * 64 + ((kb ^ ((lr >> 1) & 3)) << 4));
        }
#pragma unroll
        for (int fn = 0; fn < FN; ++fn) {
            const int n = wn * (BN / 2) + fn * 16 + lr;
            const f16x8 bf = *(const f16x8*)(Bs + buf * (BN * 64) + n * 64 + ((kb ^ ((lr >> 1) & 3)) << 4));
#pragma unroll
            for (int fm = 0; fm < 4; ++fm)
                acc[fm][fn] = __builtin_amdgcn_mfma_f32_16x16x32_f16(af[fm], bf, acc[fm][fn], 0, 0, 0);
        }
        __syncthreads();
        buf ^= 1;
    }

    const int r4 = (lane >> 4) << 2;
#pragma unroll
    for (int fm = 0; fm < 4; ++fm) {
        const int row0 = bm + wm * 64 + fm * 16 + r4;
#pragma unroll
        for (int fn = 0; fn < FN; ++fn) {
            const int col = bn + wn * (BN / 2) + fn * 16 + lr;
#pragma unroll
            for (int r = 0; r < 4; ++r) {
                float o = acc[fm][fn][r];
                if (EPI == 1) {
                    if (col < DM) o = phi_f(o) * 0.125f;
                    else if (col < 2 * DM) o = phi_f(o);
                }
                if (EPI == 2) {
                    ((float*)Cv)[(size_t)(row0 + r) * N + col] =
                        o + addx[(size_t)(row0 + r) * N + col];
                } else {
                    ((f16*)Cv)[(size_t)(row0 + r) * N + col] = (f16)o;
                }
            }
        }
    }
}

// ---------------- 4. causal dwconv + silu + gate, in-place on upg[.][2048+c] ----
__global__ __launch_bounds__(256) void conv_gate_k(f16* __restrict__ upg,
                                                   const float* __restrict__ cw,
                                                   const float* __restrict__ cb)
{
    const int row = blockIdx.x;
    const int s = row & (SEQL - 1);
    const int c = threadIdx.x * 8;
    float a[8];
    {
        const float4 b0 = *(const float4*)(cb + c);
        const float4 b1 = *(const float4*)(cb + c + 4);
        a[0] = b0.x; a[1] = b0.y; a[2] = b0.z; a[3] = b0.w;
        a[4] = b1.x; a[5] = b1.y; a[6] = b1.z; a[7] = b1.w;
    }
    float tap[8][4];
#pragma unroll
    for (int j = 0; j < 8; ++j)
        *(float4*)tap[j] = *(const float4*)(cw + (size_t)(c + j) * 4);
#pragma unroll
    for (int jt = 0; jt < 4; ++jt) {
        const int sj = s - 3 + jt;
        if (sj >= 0) {
            const f16x8 u = *(const f16x8*)(upg + (size_t)(row - 3 + jt) * 4096 + c);
#pragma unroll
            for (int j = 0; j < 8; ++j) a[j] = fmaf((float)u[j], tap[j][jt], a[j]);
        }
    }
    const f16x8 g = *(const f16x8*)(upg + (size_t)row * 4096 + 2048 + c);
    f16x8 o;
#pragma unroll
    for (int j = 0; j < 8; ++j) o[j] = (f16)(silu_f((float)g[j]) * silu_f(a[j]));
    *(f16x8*)(upg + (size_t)row * 4096 + 2048 + c) = o;
}

// ---------------- 5a. per-chunk outer products: G[h][ch] = K^T V ----------------
__global__ __launch_bounds__(256) void gscan_g_k(const f16* __restrict__ qkv,
                                                 float* __restrict__ G)
{
    __shared__ float Ks[4096];
    __shared__ float Vs[4096];
    const int t = threadIdx.x, ch = blockIdx.x, h = blockIdx.y;
    const int r = t >> 2, c16 = (t & 3) * 16;
    const f16* kp = qkv + (size_t)(ch * 64 + r) * 3072 + DM + h * 64 + c16;
#pragma unroll
    for (int i = 0; i < 2; ++i) {
        const f16x8 kv = *(const f16x8*)(kp + 8 * i);
        const f16x8 vv = *(const f16x8*)(kp + DM + 8 * i);
#pragma unroll
        for (int j = 0; j < 8; ++j) {
            Ks[r * 64 + c16 + 8 * i + j] = (float)kv[j];
            Vs[r * 64 + c16 + 8 * i + j] = (float)vv[j];
        }
    }
    __syncthreads();
    const int d4 = (t >> 4) * 4, e4 = (t & 15) * 4;
    float4 ag[4] = {};
#pragma unroll 4
    for (int c = 0; c < 64; ++c) {
        float ka[4];
        *(float4*)ka = *(const float4*)(Ks + c * 64 + d4);
        const float4 va = *(const float4*)(Vs + c * 64 + e4);
        FMA4(ag[0], ka[0], va);
        FMA4(ag[1], ka[1], va);
        FMA4(ag[2], ka[2], va);
        FMA4(ag[3], ka[3], va);
    }
    float* go = G + ((size_t)h * 64 + ch) * 4096 + d4 * 64 + e4;
#pragma unroll
    for (int i = 0; i < 4; ++i) *(float4*)(go + i * 64) = ag[i];
}

// ---------------- 5b. in-place exclusive prefix over chunks ---------------------
__global__ __launch_bounds__(256) void gprefix_k(float* __restrict__ G)
{
    const int h = blockIdx.x >> 4, sl = blockIdx.x & 15;
    const int idx = sl * 256 + threadIdx.x;
    float run = 0.0f;
    float* p = G + (size_t)h * 64 * 4096 + idx;
#pragma unroll 4
    for (int ch = 0; ch < 64; ++ch) {
        const float g = *p;
        *p = run;
        run += g;
        p += 4096;
    }
}

// ---------------- 5c. per-chunk read: y = q*M_excl + tril(q k^T) v --------------
__global__ __launch_bounds__(256) void gscan_y_k(const f16* __restrict__ qkv,
                                                 const float* __restrict__ G,
                                                 f16* __restrict__ y)
{
    __shared__ float qT[4096];   // qT[d][c]; later scT[e][c]
    __shared__ float Kd[4096];   // Kd[d][e] = K[e][d]
    __shared__ float Vs[4096];
    __shared__ float Ms[4096];
    const int t = threadIdx.x, ch = blockIdx.x, h = blockIdx.y;
    const int r = t >> 2, c16 = (t & 3) * 16;
    const f16* qp = qkv + (size_t)(ch * 64 + r) * 3072 + h * 64 + c16;
#pragma unroll
    for (int i = 0; i < 2; ++i) {
        const f16x8 qv = *(const f16x8*)(qp + 8 * i);
        const f16x8 kv = *(const f16x8*)(qp + DM + 8 * i);
        const f16x8 vv = *(const f16x8*)(qp + 2 * DM + 8 * i);
#pragma unroll
        for (int j = 0; j < 8; ++j) {
            qT[(c16 + 8 * i + j) * 64 + r] = (float)qv[j];
            Kd[(c16 + 8 * i + j) * 64 + r] = (float)kv[j];
            Vs[r * 64 + c16 + 8 * i + j] = (float)vv[j];
        }
    }
    const float* mg = G + ((size_t)h * 64 + ch) * 4096;
#pragma unroll
    for (int i = 0; i < 4; ++i)
        *(float4*)(Ms + t * 16 + 4 * i) = *(const float4*)(mg + t * 16 + 4 * i);
    __syncthreads();

    const int c4 = (t >> 4) * 4, e4 = (t & 15) * 4;
    float sa[4][4] = {}, ya[4][4] = {};
#pragma unroll 2
    for (int d = 0; d < 64; ++d) {
        float a[4], b[4], m[4];
        *(float4*)a = *(const float4*)(qT + d * 64 + c4);
        *(float4*)b = *(const float4*)(Kd + d * 64 + e4);
        *(float4*)m = *(const float4*)(Ms + d * 64 + e4);
#pragma unroll
        for (int i = 0; i < 4; ++i)
#pragma unroll
            for (int j = 0; j < 4; ++j) {
                sa[i][j] = fmaf(a[i], b[j], sa[i][j]);
                ya[i][j] = fmaf(a[i], m[j], ya[i][j]);
            }
    }
#pragma unroll
    for (int i = 0; i < 4; ++i)
#pragma unroll
        for (int j = 0; j < 4; ++j)
            if (e4 + j > c4 + i) sa[i][j] = 0.0f;
    __syncthreads();
#pragma unroll
    for (int i = 0; i < 4; ++i)
#pragma unroll
        for (int j = 0; j < 4; ++j)
            qT[(e4 + j) * 64 + c4 + i] = sa[i][j];
    __syncthreads();
#pragma unroll 2
    for (int e = 0; e < 64; ++e) {
        float a[4], vv[4];
        *(float4*)a = *(const float4*)(qT + e * 64 + c4);
        *(float4*)vv = *(const float4*)(Vs + e * 64 + e4);
#pragma unroll
        for (int i = 0; i < 4; ++i)
#pragma unroll
            for (int j = 0; j < 4; ++j)
                ya[i][j] = fmaf(a[i], vv[j], ya[i][j]);
    }
#pragma unroll
    for (int i = 0; i < 4; ++i) {
        f16x4 o;
        o[0] = (f16)ya[i][0]; o[1] = (f16)ya[i][1];
        o[2] = (f16)ya[i][2]; o[3] = (f16)ya[i][3];
        *(f16x4*)(y + (size_t)(ch * 64 + c4 + i) * DM + h * 64 + e4) = o;
    }
}

// ---------------- launch --------------------------------------------------------
extern "C" void kernel_launch(void* const* d_in, const int* in_sizes, int n_in,
                              void* d_out, int out_size, void* d_ws, size_t ws_size,
                              hipStream_t stream)
{
    const float* x      = (const float*)d_in[0];
    const float* norm_w = (const float*)d_in[1];
    const float* w_up   = (const float*)d_in[2];
    const float* w_gate = (const float*)d_in[3];
    const float* w_down = (const float*)d_in[4];
    const float* conv_w = (const float*)d_in[5];
    const float* conv_b = (const float*)d_in[6];
    const float* wq     = (const float*)d_in[7];
    const float* wk     = (const float*)d_in[8];
    const float* wv     = (const float*)d_in[9];
    const float* wo     = (const float*)d_in[10];
    float* out = (float*)d_out;
    char* p = (char*)d_ws;

    const size_t MB = 1024 * 1024;
    const bool big = ws_size >= (size_t)(240 * MB);

    // common: xn (all rows, f16) + fmt buffers
    f16* xn = (f16*)p;                         p += (size_t)NRALL * DM * 2;        // 32MB
    // R1: upgate (rows x 4096 f16) -> later qkv (rows x 3072 f16)
    const size_t rows = big ? NRALL : SEQL;
    f16* upg = (f16*)p;                        p += rows * 4096 * 2;               // 128 / 32 MB
    f16* hb  = (f16*)p;                        p += rows * DM * 2;                 // 32 / 8 MB (h -> y)
    float* G = (float*)p;                      p += (size_t)16 * 64 * 4096 * 4;    // 16.8MB
    char* fmtUG  = p;                          p += (size_t)32 * 4096 * 64;        // 8MB
    char* fmtD   = p;                          p += (size_t)64 * 1024 * 64;        // 4MB
    char* fmtQKV = p;                          p += (size_t)32 * 3072 * 64;        // 6MB
    char* fmtO   = p;                          /* 2MB */

    f16* qkvb = upg;   // reuse R1
    f16* yb   = hb;    // reuse R2

    rmsnorm_k<<<NRALL, 256, 0, stream>>>(x, norm_w, xn);

    wfmt_k<<<dim3(8, 32), 256, 0, stream>>>(w_up,   fmtUG,  DI, 4096, 0);
    wfmt_k<<<dim3(8, 32), 256, 0, stream>>>(w_gate, fmtUG,  DI, 4096, 2048);
    wfmt_k<<<dim3(4, 64), 256, 0, stream>>>(w_down, fmtD,   DM, 1024, 0);
    wfmt_k<<<dim3(4, 32), 256, 0, stream>>>(wq,     fmtQKV, DM, 3072, 0);
    wfmt_k<<<dim3(4, 32), 256, 0, stream>>>(wk,     fmtQKV, DM, 3072, 1024);
    wfmt_k<<<dim3(4, 32), 256, 0, stream>>>(wv,     fmtQKV, DM, 3072, 2048);
    wfmt_k<<<dim3(4, 32), 256, 0, stream>>>(wo,     fmtO,   DM, 1024, 0);

    if (big) {
        const int gy = NRALL / 128;  // 128
        mgemm16_k<128, 0><<<32 * gy, 256, 0, stream>>>(xn, DM, fmtUG, upg, 4096, DM, gy, nullptr);
        conv_gate_k<<<NRALL, 256, 0, stream>>>(upg, conv_w, conv_b);
        mgemm16_k<128, 0><<<8 * gy, 256, 0, stream>>>(upg + 2048, 4096, fmtD, hb, 1024, DI, gy, nullptr);
        mgemm16_k<128, 1><<<24 * gy, 256, 0, stream>>>(hb, DM, fmtQKV, qkvb, 3072, DM, gy, nullptr);
        for (int b = 0; b < 4; ++b) {
            const f16* qkv_b = qkvb + (size_t)b * SEQL * 3072;
            gscan_g_k<<<dim3(64, 16), 256, 0, stream>>>(qkv_b, G);
            gprefix_k<<<256, 256, 0, stream>>>(G);
            gscan_y_k<<<dim3(64, 16), 256, 0, stream>>>(qkv_b, G, yb + (size_t)b * SEQL * DM);
        }
        mgemm16_k<128, 2><<<8 * gy, 256, 0, stream>>>(yb, DM, fmtO, out, 1024, DM, gy, x);
    } else {
        const int gy = SEQL / 128;   // 32
        for (int b = 0; b < 4; ++b) {
            const f16* xnb = xn + (size_t)b * SEQL * DM;
            mgemm16_k<128, 0><<<32 * gy, 256, 0, stream>>>(xnb, DM, fmtUG, upg, 4096, DM, gy, nullptr);
            conv_gate_k<<<SEQL, 256, 0, stream>>>(upg, conv_w, conv_b);
            mgemm16_k<64, 0><<<16 * gy, 256, 0, stream>>>(upg + 2048, 4096, fmtD, hb, 1024, DI, gy, nullptr);
            mgemm16_k<128, 1><<<24 * gy, 256, 0, stream>>>(hb, DM, fmtQKV, qkvb, 3072, DM, gy, nullptr);
            gscan_g_k<<<dim3(64, 16), 256, 0, stream>>>(qkvb, G);
            gprefix_k<<<256, 256, 0, stream>>>(G);
            gscan_y_k<<<dim3(64, 16), 256, 0, stream>>>(qkvb, G, yb);
            mgemm16_k<64, 2><<<16 * gy, 256, 0, stream>>>(yb, DM, fmtO,
                                                          out + (size_t)b * SEQL * DM, 1024, DM, gy,
                                                          x + (size_t)b * SEQL * DM);
        }
    }
}

// Round 5
// 744.593 us; speedup vs baseline: 7.6033x; 1.1511x over previous
//
#include <hip/hip_runtime.h>
#include <hip/hip_fp16.h>
#include <cstdint>

// Problem constants (B=4, S=4096, D=1024)
#define NRALL 16384
#define DM    1024
#define DI    2048
#define SEQL  4096

typedef _Float16 f16;
typedef _Float16 f16x8 __attribute__((ext_vector_type(8)));
typedef _Float16 f16x4 __attribute__((ext_vector_type(4)));
typedef float    f32x4 __attribute__((ext_vector_type(4)));

__device__ __forceinline__ float phi_f(float t)  { return t > 0.0f ? t + 1.0f : __expf(t); }
__device__ __forceinline__ float silu_f(float t) { return t / (1.0f + __expf(-t)); }

#define GLDS16(g, l)                                                            \
    __builtin_amdgcn_global_load_lds(                                           \
        (const __attribute__((address_space(1))) void*)(g),                     \
        (__attribute__((address_space(3))) void*)(l), 16, 0, 0)

#define FMA4(dst, s, vv)                      \
    dst.x = fmaf((s), (vv).x, dst.x);         \
    dst.y = fmaf((s), (vv).y, dst.y);         \
    dst.z = fmaf((s), (vv).z, dst.z);         \
    dst.w = fmaf((s), (vv).w, dst.w);

// ---------------- 1. rmsnorm -> f16 --------------------------------------------
__global__ __launch_bounds__(256) void rmsnorm_k(const float* __restrict__ x,
                                                 const float* __restrict__ nw,
                                                 f16* __restrict__ xn)
{
    const int r = blockIdx.x, t = threadIdx.x;
    const float4 v = *(const float4*)(x + (size_t)r * DM + t * 4);
    float s = v.x * v.x + v.y * v.y + v.z * v.z + v.w * v.w;
#pragma unroll
    for (int m = 1; m < 64; m <<= 1) s += __shfl_xor(s, m);
    __shared__ float ws4[4];
    if ((t & 63) == 0) ws4[t >> 6] = s;
    __syncthreads();
    const float tot = ws4[0] + ws4[1] + ws4[2] + ws4[3];
    const float sc = rsqrtf(tot * (1.0f / DM) + 1e-5f);
    const float4 w = *(const float4*)(nw + t * 4);
    f16x4 o;
    o[0] = (f16)(v.x * sc * w.x); o[1] = (f16)(v.y * sc * w.y);
    o[2] = (f16)(v.z * sc * w.z); o[3] = (f16)(v.w * sc * w.w);
    *(f16x4*)(xn + (size_t)r * DM + t * 4) = o;
}

// ---------------- 2. merged weight format (all 7 weights, one launch) -----------
// fmt[(kt*Ntot + ng)*64 + slot*16] holds 8 f16 of k = kt*32 + (slot^((ng>>1)&3))*8..+7
__device__ __forceinline__ void wfmt_one(const float* __restrict__ W, char* __restrict__ fmt,
                                         int n, int kt, int Nw, int Ntot, int noff)
{
    const int ng = noff + n;
    char* o = fmt + ((size_t)kt * Ntot + ng) * 64;
#pragma unroll
    for (int c = 0; c < 4; ++c) {
        f16x8 p;
#pragma unroll
        for (int j = 0; j < 8; ++j)
            p[j] = (f16)W[(size_t)(kt * 32 + c * 8 + j) * Nw + n];
        *(f16x8*)(o + ((c ^ ((ng >> 1) & 3)) << 4)) = p;
    }
}

__global__ __launch_bounds__(256) void wfmt_all_k(const float* __restrict__ w_up,
                                                  const float* __restrict__ w_gate,
                                                  const float* __restrict__ w_down,
                                                  const float* __restrict__ wq,
                                                  const float* __restrict__ wk,
                                                  const float* __restrict__ wv,
                                                  const float* __restrict__ wo,
                                                  char* __restrict__ fmtUG,
                                                  char* __restrict__ fmtD,
                                                  char* __restrict__ fmtQKV,
                                                  char* __restrict__ fmtO)
{
    int id = blockIdx.x;
    const int t = threadIdx.x;
    if (id < 256)      { wfmt_one(w_up,   fmtUG,  (id % 8) * 256 + t, id / 8, DI, 4096, 0);    return; }
    id -= 256;
    if (id < 256)      { wfmt_one(w_gate, fmtUG,  (id % 8) * 256 + t, id / 8, DI, 4096, 2048); return; }
    id -= 256;
    if (id < 256)      { wfmt_one(w_down, fmtD,   (id % 4) * 256 + t, id / 4, DM, 1024, 0);    return; }
    id -= 256;
    if (id < 128)      { wfmt_one(wq,     fmtQKV, (id % 4) * 256 + t, id / 4, DM, 3072, 0);    return; }
    id -= 128;
    if (id < 128)      { wfmt_one(wk,     fmtQKV, (id % 4) * 256 + t, id / 4, DM, 3072, 1024); return; }
    id -= 128;
    if (id < 128)      { wfmt_one(wv,     fmtQKV, (id % 4) * 256 + t, id / 4, DM, 3072, 2048); return; }
    id -= 128;
    wfmt_one(wo, fmtO, (id % 4) * 256 + t, id / 4, DM, 1024, 0);
}

// ---------------- 3. f16 MFMA GEMM, 128xBN tile, BK=32, dbuf glds staging -------
// Row-band-major block order (consecutive blocks share the A band, stream B ->
// resident working set ~ A-band + full B, L2-sized). Bijective XCD swizzle.
// EPI: 0 f16 out; 1 qkv epilogue (phi*0.125 | phi | id by col range), f16 out;
//      2 +addx, fp32 out.
template <int BN, int EPI>
__global__ __launch_bounds__(256, 4) void mgemm16_k(const f16* __restrict__ A, int lda,
                                                    const char* __restrict__ fmt,
                                                    void* __restrict__ Cv,
                                                    int N, int K, int gx,
                                                    const float* __restrict__ addx)
{
    constexpr int FN = BN / 32;
    constexpr int BROUNDS = (BN * 64) / 4096;
    __shared__ char lds[BN == 128 ? 32768 : 24576];
    char* As = lds;            // 2 x 8KB
    char* Bs = lds + 16384;    // 2 x BN*64

    const int t = threadIdx.x;
    int wid = blockIdx.x;
    { const int cpx = gridDim.x >> 3; wid = (wid & 7) * cpx + (wid >> 3); }  // XCD swizzle
    const int bx = wid % gx, by = wid / gx;
    const int bm = by * 128, bn = bx * BN;
    const int lane = t & 63, wv = t >> 6;
    const int wm = wv >> 1, wn = wv & 1;
    const int kb = lane >> 4, lr = lane & 15;
    const int NT = K >> 5;

    f32x4 acc[4][FN];
#pragma unroll
    for (int i = 0; i < 4; ++i)
#pragma unroll
        for (int j = 0; j < FN; ++j) acc[i][j] = (f32x4)0.0f;

    auto STAGE = [&](int buf, int kt) {
#pragma unroll
        for (int r = 0; r < 2; ++r) {
            const int id = t + 256 * r;
            const int row = id >> 2, sl = id & 3;
            const f16* src = A + (size_t)(bm + row) * lda + kt * 32 + ((sl ^ ((row >> 1) & 3)) << 3);
            GLDS16(src, As + buf * 8192 + ((wv * 64 + 256 * r) << 4));
        }
#pragma unroll
        for (int r = 0; r < BROUNDS; ++r) {
            const char* src = fmt + ((size_t)kt * N + bn) * 64 + (size_t)(t + 256 * r) * 16;
            GLDS16(src, Bs + buf * (BN * 64) + ((wv * 64 + 256 * r) << 4));
        }
    };

    STAGE(0, 0);
    __syncthreads();
    int buf = 0;
    for (int kt = 0; kt < NT; ++kt) {
        if (kt + 1 < NT) STAGE(buf ^ 1, kt + 1);
        f16x8 af[4];
#pragma unroll
        for (int fm = 0; fm < 4; ++fm) {
            const int row = wm * 64 + fm * 16 + lr;
            af[fm] = *(const f16x8*)(As + buf * 8192 + row * 64 + ((kb ^ ((lr >> 1) & 3)) << 4));
        }
#pragma unroll
        for (int fn = 0; fn < FN; ++fn) {
            const int n = wn * (BN / 2) + fn * 16 + lr;
            const f16x8 bf = *(const f16x8*)(Bs + buf * (BN * 64) + n * 64 + ((kb ^ ((lr >> 1) & 3)) << 4));
#pragma unroll
            for (int fm = 0; fm < 4; ++fm)
                acc[fm][fn] = __builtin_amdgcn_mfma_f32_16x16x32_f16(af[fm], bf, acc[fm][fn], 0, 0, 0);
        }
        __syncthreads();
        buf ^= 1;
    }

    const int r4 = (lane >> 4) << 2;
#pragma unroll
    for (int fm = 0; fm < 4; ++fm) {
        const int row0 = bm + wm * 64 + fm * 16 + r4;
#pragma unroll
        for (int fn = 0; fn < FN; ++fn) {
            const int col = bn + wn * (BN / 2) + fn * 16 + lr;
#pragma unroll
            for (int r = 0; r < 4; ++r) {
                float o = acc[fm][fn][r];
                if (EPI == 1) {
                    if (col < DM) o = phi_f(o) * 0.125f;
                    else if (col < 2 * DM) o = phi_f(o);
                }
                if (EPI == 2) {
                    ((float*)Cv)[(size_t)(row0 + r) * N + col] =
                        o + addx[(size_t)(row0 + r) * N + col];
                } else {
                    ((f16*)Cv)[(size_t)(row0 + r) * N + col] = (f16)o;
                }
            }
        }
    }
}

// ---------------- 4. causal dwconv + silu + gate, in-place on upg[.][2048+c] ----
__global__ __launch_bounds__(256) void conv_gate_k(f16* __restrict__ upg,
                                                   const float* __restrict__ cw,
                                                   const float* __restrict__ cb)
{
    const int row = blockIdx.x;
    const int s = row & (SEQL - 1);
    const int c = threadIdx.x * 8;
    float a[8];
    {
        const float4 b0 = *(const float4*)(cb + c);
        const float4 b1 = *(const float4*)(cb + c + 4);
        a[0] = b0.x; a[1] = b0.y; a[2] = b0.z; a[3] = b0.w;
        a[4] = b1.x; a[5] = b1.y; a[6] = b1.z; a[7] = b1.w;
    }
    float tap[8][4];
#pragma unroll
    for (int j = 0; j < 8; ++j)
        *(float4*)tap[j] = *(const float4*)(cw + (size_t)(c + j) * 4);
#pragma unroll
    for (int jt = 0; jt < 4; ++jt) {
        const int sj = s - 3 + jt;
        if (sj >= 0) {
            const f16x8 u = *(const f16x8*)(upg + (size_t)(row - 3 + jt) * 4096 + c);
#pragma unroll
            for (int j = 0; j < 8; ++j) a[j] = fmaf((float)u[j], tap[j][jt], a[j]);
        }
    }
    const f16x8 g = *(const f16x8*)(upg + (size_t)row * 4096 + 2048 + c);
    f16x8 o;
#pragma unroll
    for (int j = 0; j < 8; ++j) o[j] = (f16)(silu_f((float)g[j]) * silu_f(a[j]));
    *(f16x8*)(upg + (size_t)row * 4096 + 2048 + c) = o;
}

// ---------------- 5a. per-chunk outer products: G[b][h][ch] = K^T V -------------
__global__ __launch_bounds__(256) void gscan_g_k(const f16* __restrict__ qkv,
                                                 float* __restrict__ G)
{
    __shared__ float Ks[4096];
    __shared__ float Vs[4096];
    const int t = threadIdx.x, ch = blockIdx.x, h = blockIdx.y, b = blockIdx.z;
    const int r = t >> 2, c16 = (t & 3) * 16;
    const f16* kp = qkv + ((size_t)b * SEQL + ch * 64 + r) * 3072 + DM + h * 64 + c16;
#pragma unroll
    for (int i = 0; i < 2; ++i) {
        const f16x8 kv = *(const f16x8*)(kp + 8 * i);
        const f16x8 vv = *(const f16x8*)(kp + DM + 8 * i);
#pragma unroll
        for (int j = 0; j < 8; ++j) {
            Ks[r * 64 + c16 + 8 * i + j] = (float)kv[j];
            Vs[r * 64 + c16 + 8 * i + j] = (float)vv[j];
        }
    }
    __syncthreads();
    const int d4 = (t >> 4) * 4, e4 = (t & 15) * 4;
    float4 ag[4] = {};
#pragma unroll 4
    for (int c = 0; c < 64; ++c) {
        float ka[4];
        *(float4*)ka = *(const float4*)(Ks + c * 64 + d4);
        const float4 va = *(const float4*)(Vs + c * 64 + e4);
        FMA4(ag[0], ka[0], va);
        FMA4(ag[1], ka[1], va);
        FMA4(ag[2], ka[2], va);
        FMA4(ag[3], ka[3], va);
    }
    float* go = G + (((size_t)b * 16 + h) * 64 + ch) * 4096 + d4 * 64 + e4;
#pragma unroll
    for (int i = 0; i < 4; ++i) *(float4*)(go + i * 64) = ag[i];
}

// ---------------- 5b. in-place exclusive prefix over chunks ---------------------
// one block per (slab bh = b*16+h, 256-col slice sl)
__global__ __launch_bounds__(256) void gprefix_k(float* __restrict__ G)
{
    const int bh = blockIdx.x >> 4, sl = blockIdx.x & 15;
    const int idx = sl * 256 + threadIdx.x;
    float run = 0.0f;
    float* p = G + (size_t)bh * 64 * 4096 + idx;
#pragma unroll 4
    for (int ch = 0; ch < 64; ++ch) {
        const float g = *p;
        *p = run;
        run += g;
        p += 4096;
    }
}

// ---------------- 5c. per-chunk read: y = q*M_excl + tril(q k^T) v --------------
__global__ __launch_bounds__(256) void gscan_y_k(const f16* __restrict__ qkv,
                                                 const float* __restrict__ G,
                                                 f16* __restrict__ y)
{
    __shared__ float qT[4096];   // qT[d][c]; later scT[e][c]
    __shared__ float Kd[4096];   // Kd[d][e] = K[e][d]
    __shared__ float Vs[4096];
    __shared__ float Ms[4096];
    const int t = threadIdx.x, ch = blockIdx.x, h = blockIdx.y, b = blockIdx.z;
    const int r = t >> 2, c16 = (t & 3) * 16;
    const f16* qp = qkv + ((size_t)b * SEQL + ch * 64 + r) * 3072 + h * 64 + c16;
#pragma unroll
    for (int i = 0; i < 2; ++i) {
        const f16x8 qv = *(const f16x8*)(qp + 8 * i);
        const f16x8 kv = *(const f16x8*)(qp + DM + 8 * i);
        const f16x8 vv = *(const f16x8*)(qp + 2 * DM + 8 * i);
#pragma unroll
        for (int j = 0; j < 8; ++j) {
            qT[(c16 + 8 * i + j) * 64 + r] = (float)qv[j];
            Kd[(c16 + 8 * i + j) * 64 + r] = (float)kv[j];
            Vs[r * 64 + c16 + 8 * i + j] = (float)vv[j];
        }
    }
    const float* mg = G + (((size_t)b * 16 + h) * 64 + ch) * 4096;
#pragma unroll
    for (int i = 0; i < 4; ++i)
        *(float4*)(Ms + t * 16 + 4 * i) = *(const float4*)(mg + t * 16 + 4 * i);
    __syncthreads();

    const int c4 = (t >> 4) * 4, e4 = (t & 15) * 4;
    float sa[4][4] = {}, ya[4][4] = {};
#pragma unroll 2
    for (int d = 0; d < 64; ++d) {
        float a[4], bb[4], m[4];
        *(float4*)a = *(const float4*)(qT + d * 64 + c4);
        *(float4*)bb = *(const float4*)(Kd + d * 64 + e4);
        *(float4*)m = *(const float4*)(Ms + d * 64 + e4);
#pragma unroll
        for (int i = 0; i < 4; ++i)
#pragma unroll
            for (int j = 0; j < 4; ++j) {
                sa[i][j] = fmaf(a[i], bb[j], sa[i][j]);
                ya[i][j] = fmaf(a[i], m[j], ya[i][j]);
            }
    }
#pragma unroll
    for (int i = 0; i < 4; ++i)
#pragma unroll
        for (int j = 0; j < 4; ++j)
            if (e4 + j > c4 + i) sa[i][j] = 0.0f;
    __syncthreads();
#pragma unroll
    for (int i = 0; i < 4; ++i)
#pragma unroll
        for (int j = 0; j < 4; ++j)
            qT[(e4 + j) * 64 + c4 + i] = sa[i][j];
    __syncthreads();
#pragma unroll 2
    for (int e = 0; e < 64; ++e) {
        float a[4], vv[4];
        *(float4*)a = *(const float4*)(qT + e * 64 + c4);
        *(float4*)vv = *(const float4*)(Vs + e * 64 + e4);
#pragma unroll
        for (int i = 0; i < 4; ++i)
#pragma unroll
            for (int j = 0; j < 4; ++j)
                ya[i][j] = fmaf(a[i], vv[j], ya[i][j]);
    }
#pragma unroll
    for (int i = 0; i < 4; ++i) {
        f16x4 o;
        o[0] = (f16)ya[i][0]; o[1] = (f16)ya[i][1];
        o[2] = (f16)ya[i][2]; o[3] = (f16)ya[i][3];
        *(f16x4*)(y + ((size_t)b * SEQL + ch * 64 + c4 + i) * DM + h * 64 + e4) = o;
    }
}

// ---------------- launch --------------------------------------------------------
extern "C" void kernel_launch(void* const* d_in, const int* in_sizes, int n_in,
                              void* d_out, int out_size, void* d_ws, size_t ws_size,
                              hipStream_t stream)
{
    const float* x      = (const float*)d_in[0];
    const float* norm_w = (const float*)d_in[1];
    const float* w_up   = (const float*)d_in[2];
    const float* w_gate = (const float*)d_in[3];
    const float* w_down = (const float*)d_in[4];
    const float* conv_w = (const float*)d_in[5];
    const float* conv_b = (const float*)d_in[6];
    const float* wq     = (const float*)d_in[7];
    const float* wk     = (const float*)d_in[8];
    const float* wv     = (const float*)d_in[9];
    const float* wo     = (const float*)d_in[10];
    float* out = (float*)d_out;

    const size_t BIG_NEED = 247463936ull;   // see layout below
    const bool big = ws_size >= BIG_NEED;

    if (big) {
        // layout (bytes):
        //   upg    [0,       134.2M)   up|gate rows x4096 f16 -> later qkv rows x3072
        //   hb     [134.2M,  +33.6M)   h f16 -> later y f16
        //   fmtD   [+4.2M) fmtQKV [+6.3M) fmtO [+2.1M)
        //   xn     [180.4M,  +33.6M)   dead after up/gate GEMM
        //   fmtUG  [213.9M,  +8.4M)    dead after up/gate GEMM
        //   G overlays xn..247.5M (67.1M, live only during scan)
        char* p = (char*)d_ws;
        f16* upg = (f16*)p;               p += (size_t)NRALL * 4096 * 2;
        f16* hb  = (f16*)p;               p += (size_t)NRALL * DM * 2;
        char* fmtD   = p;                 p += (size_t)64 * 1024 * 64;
        char* fmtQKV = p;                 p += (size_t)32 * 3072 * 64;
        char* fmtO   = p;                 p += (size_t)32 * 1024 * 64;
        f16* xn = (f16*)p;                p += (size_t)NRALL * DM * 2;
        char* fmtUG  = p;
        float* G = (float*)xn;            // 4*16*64*4096 floats
        f16* qkvb = upg;
        f16* yb   = hb;

        rmsnorm_k<<<NRALL, 256, 0, stream>>>(x, norm_w, xn);
        wfmt_all_k<<<1280, 256, 0, stream>>>(w_up, w_gate, w_down, wq, wk, wv, wo,
                                             fmtUG, fmtD, fmtQKV, fmtO);

        mgemm16_k<128, 0><<<4096, 256, 0, stream>>>(xn, DM, fmtUG, upg, 4096, DM, 32, nullptr);
        conv_gate_k<<<NRALL, 256, 0, stream>>>(upg, conv_w, conv_b);
        mgemm16_k<128, 0><<<1024, 256, 0, stream>>>(upg + 2048, 4096, fmtD, hb, 1024, DI, 8, nullptr);
        mgemm16_k<128, 1><<<3072, 256, 0, stream>>>(hb, DM, fmtQKV, qkvb, 3072, DM, 24, nullptr);

        gscan_g_k<<<dim3(64, 16, 4), 256, 0, stream>>>(qkvb, G);
        gprefix_k<<<1024, 256, 0, stream>>>(G);
        gscan_y_k<<<dim3(64, 16, 4), 256, 0, stream>>>(qkvb, G, yb);

        mgemm16_k<128, 2><<<1024, 256, 0, stream>>>(yb, DM, fmtO, out, 1024, DM, 8, x);
    } else {
        // compact per-batch path (~113 MB)
        char* p = (char*)d_ws;
        f16* xn = (f16*)p;                p += (size_t)NRALL * DM * 2;
        f16* upg = (f16*)p;               p += (size_t)SEQL * 4096 * 2;
        f16* hb  = (f16*)p;               p += (size_t)SEQL * DM * 2;
        float* G = (float*)p;             p += (size_t)16 * 64 * 4096 * 4;
        char* fmtUG  = p;                 p += (size_t)32 * 4096 * 64;
        char* fmtD   = p;                 p += (size_t)64 * 1024 * 64;
        char* fmtQKV = p;                 p += (size_t)32 * 3072 * 64;
        char* fmtO   = p;
        f16* qkvb = upg;
        f16* yb   = hb;

        rmsnorm_k<<<NRALL, 256, 0, stream>>>(x, norm_w, xn);
        wfmt_all_k<<<1280, 256, 0, stream>>>(w_up, w_gate, w_down, wq, wk, wv, wo,
                                             fmtUG, fmtD, fmtQKV, fmtO);

        for (int b = 0; b < 4; ++b) {
            const f16* xnb = xn + (size_t)b * SEQL * DM;
            mgemm16_k<128, 0><<<1024, 256, 0, stream>>>(xnb, DM, fmtUG, upg, 4096, DM, 32, nullptr);
            conv_gate_k<<<SEQL, 256, 0, stream>>>(upg, conv_w, conv_b);
            mgemm16_k<64, 0><<<512, 256, 0, stream>>>(upg + 2048, 4096, fmtD, hb, 1024, DI, 16, nullptr);
            mgemm16_k<128, 1><<<768, 256, 0, stream>>>(hb, DM, fmtQKV, qkvb, 3072, DM, 24, nullptr);
            gscan_g_k<<<dim3(64, 16, 1), 256, 0, stream>>>(qkvb, G);
            gprefix_k<<<256, 256, 0, stream>>>(G);
            gscan_y_k<<<dim3(64, 16, 1), 256, 0, stream>>>(qkvb, G, yb);
            mgemm16_k<64, 2><<<512, 256, 0, stream>>>(yb, DM, fmtO,
                                                      out + (size_t)b * SEQL * DM, 1024, DM, 16,
                                                      x + (size_t)b * SEQL * DM);
        }
    }
}

// Round 6
// 701.578 us; speedup vs baseline: 8.0695x; 1.0613x over previous
//
#include <hip/hip_runtime.h>
#include <hip/hip_fp16.h>
#include <cstdint>

// Problem constants (B=4, S=4096, D=1024)
#define NRALL 16384
#define DM    1024
#define DI    2048
#define SEQL  4096

typedef _Float16 f16;
typedef _Float16 f16x8 __attribute__((ext_vector_type(8)));
typedef _Float16 f16x4 __attribute__((ext_vector_type(4)));
typedef float    f32x4 __attribute__((ext_vector_type(4)));

__device__ __forceinline__ float phi_f(float t)  { return t > 0.0f ? t + 1.0f : __expf(t); }
__device__ __forceinline__ float silu_f(float t) { return t / (1.0f + __expf(-t)); }

#define GLDS16(g, l)                                                            \
    __builtin_amdgcn_global_load_lds(                                           \
        (const __attribute__((address_space(1))) void*)(g),                     \
        (__attribute__((address_space(3))) void*)(l), 16, 0, 0)

#define FMA4(dst, s, vv)                      \
    dst.x = fmaf((s), (vv).x, dst.x);         \
    dst.y = fmaf((s), (vv).y, dst.y);         \
    dst.z = fmaf((s), (vv).z, dst.z);         \
    dst.w = fmaf((s), (vv).w, dst.w);

// ---------------- 1. rmsnorm -> f16 --------------------------------------------
__global__ __launch_bounds__(256) void rmsnorm_k(const float* __restrict__ x,
                                                 const float* __restrict__ nw,
                                                 f16* __restrict__ xn)
{
    const int r = blockIdx.x, t = threadIdx.x;
    const float4 v = *(const float4*)(x + (size_t)r * DM + t * 4);
    float s = v.x * v.x + v.y * v.y + v.z * v.z + v.w * v.w;
#pragma unroll
    for (int m = 1; m < 64; m <<= 1) s += __shfl_xor(s, m);
    __shared__ float ws4[4];
    if ((t & 63) == 0) ws4[t >> 6] = s;
    __syncthreads();
    const float tot = ws4[0] + ws4[1] + ws4[2] + ws4[3];
    const float sc = rsqrtf(tot * (1.0f / DM) + 1e-5f);
    const float4 w = *(const float4*)(nw + t * 4);
    f16x4 o;
    o[0] = (f16)(v.x * sc * w.x); o[1] = (f16)(v.y * sc * w.y);
    o[2] = (f16)(v.z * sc * w.z); o[3] = (f16)(v.w * sc * w.w);
    *(f16x4*)(xn + (size_t)r * DM + t * 4) = o;
}

// ---------------- 2. merged weight format (all 7 weights, one launch) -----------
// Layout per (kt, kh): Ntot x 64B; chunk (n, slot) holds 8 f16 of
// k = kt*64 + kh*32 + c2*8 .. +7 where c2 = slot ^ ((n>>1)&3)  (2-way-free swizzle).
__device__ __forceinline__ void wfmt_one(const float* __restrict__ W, char* __restrict__ fmt,
                                         int n, int kt, int Nw, int Ntot, int noff)
{
    const int ng = noff + n;
#pragma unroll
    for (int kh = 0; kh < 2; ++kh) {
        char* o = fmt + ((size_t)(kt * 2 + kh) * Ntot + ng) * 64;
#pragma unroll
        for (int c2 = 0; c2 < 4; ++c2) {
            f16x8 p;
#pragma unroll
            for (int j = 0; j < 8; ++j)
                p[j] = (f16)W[(size_t)(kt * 64 + kh * 32 + c2 * 8 + j) * Nw + n];
            *(f16x8*)(o + ((c2 ^ ((ng >> 1) & 3)) << 4)) = p;
        }
    }
}

__global__ __launch_bounds__(256) void wfmt_all_k(const float* __restrict__ w_up,
                                                  const float* __restrict__ w_gate,
                                                  const float* __restrict__ w_down,
                                                  const float* __restrict__ wq,
                                                  const float* __restrict__ wk,
                                                  const float* __restrict__ wv,
                                                  const float* __restrict__ wo,
                                                  char* __restrict__ fmtUG,
                                                  char* __restrict__ fmtD,
                                                  char* __restrict__ fmtQKV,
                                                  char* __restrict__ fmtO)
{
    int id = blockIdx.x;
    const int t = threadIdx.x;
    if (id < 128) { wfmt_one(w_up,   fmtUG,  (id % 8) * 256 + t, id / 8, DI, 4096, 0);    return; }
    id -= 128;
    if (id < 128) { wfmt_one(w_gate, fmtUG,  (id % 8) * 256 + t, id / 8, DI, 4096, 2048); return; }
    id -= 128;
    if (id < 128) { wfmt_one(w_down, fmtD,   (id % 4) * 256 + t, id / 4, DM, 1024, 0);    return; }
    id -= 128;
    if (id < 64)  { wfmt_one(wq,     fmtQKV, (id % 4) * 256 + t, id / 4, DM, 3072, 0);    return; }
    id -= 64;
    if (id < 64)  { wfmt_one(wk,     fmtQKV, (id % 4) * 256 + t, id / 4, DM, 3072, 1024); return; }
    id -= 64;
    if (id < 64)  { wfmt_one(wv,     fmtQKV, (id % 4) * 256 + t, id / 4, DM, 3072, 2048); return; }
    id -= 64;
    wfmt_one(wo, fmtO, (id % 4) * 256 + t, id / 4, DM, 1024, 0);
}

// ---------------- 3. 256x256 8-phase f16 MFMA GEMM (T2+T3+T4+T5) ---------------
// 512 thr = 8 waves (2m x 4n), BK=64, LDS 128KB: A/B x 2buf x 2 k-halves (16KB each).
// Per phase: {ds_read subtile | stage 1 half-tile} -> s_barrier -> lgkmcnt(0) ->
// setprio(1) 16 MFMA setprio(0) -> s_barrier. vmcnt(4) ONLY at phases 4 & 8.
// Stage slot schedule (iter i computes tiles 2i (buf0) / 2i+1 (buf1)):
//  ph1: buf1.Akh1<-t1  ph2: buf1.Bkh1<-t1  ph3: buf0.Akh0<-t2  ph4: buf0.Bkh0<-t2 +vm
//  ph5: buf0.Akh1<-t2  ph6: buf0.Bkh1<-t2  ph7: buf1.Akh0<-t3  ph8: buf1.Bkh0<-t3 +vm
// Each slot re-staged only after its last reader passed a barrier; each staged half
// has >=4 phases before its vmcnt-enforced deadline.
#define PHASE(p, ks, nh, STAGE_STMT, VM)                                          \
    {                                                                             \
        if ((nh) == 0) {                                                          \
            _Pragma("unroll")                                                     \
            for (int fm = 0; fm < 8; ++fm) {                                      \
                const int row = wm * 128 + fm * 16 + lr16;                        \
                af[fm] = *(const f16x8*)(ldsb + (p) * 32768 + (ks) * 16384        \
                          + row * 64 + ((kb ^ ((row >> 1) & 3)) << 4));           \
            }                                                                     \
        }                                                                         \
        f16x8 bq0, bq1;                                                           \
        {                                                                         \
            const int n0 = wn * 64 + ((nh) * 2 + 0) * 16 + lr16;                  \
            const int n1 = wn * 64 + ((nh) * 2 + 1) * 16 + lr16;                  \
            bq0 = *(const f16x8*)(ldsb + 65536 + (p) * 32768 + (ks) * 16384       \
                     + n0 * 64 + ((kb ^ ((n0 >> 1) & 3)) << 4));                  \
            bq1 = *(const f16x8*)(ldsb + 65536 + (p) * 32768 + (ks) * 16384       \
                     + n1 * 64 + ((kb ^ ((n1 >> 1) & 3)) << 4));                  \
        }                                                                         \
        STAGE_STMT;                                                               \
        if (VM) asm volatile("s_waitcnt vmcnt(4)" ::: "memory");                  \
        __builtin_amdgcn_s_barrier();                                             \
        asm volatile("s_waitcnt lgkmcnt(0)" ::: "memory");                        \
        __builtin_amdgcn_sched_barrier(0);                                        \
        __builtin_amdgcn_s_setprio(1);                                            \
        _Pragma("unroll")                                                         \
        for (int fm = 0; fm < 8; ++fm) {                                          \
            acc[fm][(nh) * 2 + 0] = __builtin_amdgcn_mfma_f32_16x16x32_f16(       \
                af[fm], bq0, acc[fm][(nh) * 2 + 0], 0, 0, 0);                     \
            acc[fm][(nh) * 2 + 1] = __builtin_amdgcn_mfma_f32_16x16x32_f16(       \
                af[fm], bq1, acc[fm][(nh) * 2 + 1], 0, 0, 0);                     \
        }                                                                         \
        __builtin_amdgcn_s_setprio(0);                                            \
        __builtin_amdgcn_s_barrier();                                             \
        __builtin_amdgcn_sched_barrier(0);                                        \
    }

template <int EPI>
__global__ __launch_bounds__(512, 2) void mg256_k(const f16* __restrict__ A, int lda,
                                                  const char* __restrict__ fmt,
                                                  void* __restrict__ Cv,
                                                  int N, int K, int gx,
                                                  const float* __restrict__ addx)
{
    __shared__ __align__(16) char ldsb[131072];

    const int t = threadIdx.x;
    int wid = blockIdx.x;
    { const int cpx = gridDim.x >> 3; wid = (wid & 7) * cpx + (wid >> 3); }  // XCD swizzle
    const int bx = wid % gx, by = wid / gx;
    const int bm = by * 256, bn = bx * 256;
    const int lane = t & 63, wv = t >> 6;
    const int wm = wv >> 2, wn = wv & 3;
    const int kb = lane >> 4, lr16 = lane & 15;
    const int NT = K >> 6;

    f32x4 acc[8][4];
#pragma unroll
    for (int i = 0; i < 8; ++i)
#pragma unroll
        for (int j = 0; j < 4; ++j) acc[i][j] = (f32x4)0.0f;

    auto STAGE_A = [&](int p, int kh, int kt) {
#pragma unroll
        for (int r = 0; r < 2; ++r) {
            const int idx = (r * 8 + wv) * 64;
            const int ii = idx + lane;
            const int row = ii >> 2, sl = ii & 3;
            const int c2 = sl ^ ((row >> 1) & 3);
            const f16* src = A + (size_t)(bm + row) * lda + kt * 64 + kh * 32 + c2 * 8;
            GLDS16(src, ldsb + p * 32768 + kh * 16384 + idx * 16);
        }
    };
    auto STAGE_B = [&](int p, int kh, int kt) {
#pragma unroll
        for (int r = 0; r < 2; ++r) {
            const int idx = (r * 8 + wv) * 64;
            const char* src = fmt + ((size_t)(kt * 2 + kh) * N + bn) * 64 + (size_t)(idx + lane) * 16;
            GLDS16(src, ldsb + 65536 + p * 32768 + kh * 16384 + idx * 16);
        }
    };

    // prologue: buf0 <- tile0 (all), buf1.kh0 <- tile1; wait buf0 landed (4 in flight)
    STAGE_A(0, 0, 0); STAGE_B(0, 0, 0);
    STAGE_A(0, 1, 0); STAGE_B(0, 1, 0);
    const int t1p = NT > 1 ? 1 : 0;
    STAGE_A(1, 0, t1p); STAGE_B(1, 0, t1p);
    asm volatile("s_waitcnt vmcnt(4)" ::: "memory");
    __builtin_amdgcn_s_barrier();
    __builtin_amdgcn_sched_barrier(0);

    f16x8 af[8];
    const int NI = NT >> 1;
    for (int i = 0; i < NI; ++i) {
        const int t1 = 2 * i + 1;
        const int t2 = 2 * i + 2 < NT ? 2 * i + 2 : NT - 1;
        const int t3 = 2 * i + 3 < NT ? 2 * i + 3 : NT - 1;
        PHASE(0, 0, 0, STAGE_A(1, 1, t1), 0)
        PHASE(0, 0, 1, STAGE_B(1, 1, t1), 0)
        PHASE(0, 1, 0, STAGE_A(0, 0, t2), 0)
        PHASE(0, 1, 1, STAGE_B(0, 0, t2), 1)
        PHASE(1, 0, 0, STAGE_A(0, 1, t2), 0)
        PHASE(1, 0, 1, STAGE_B(0, 1, t2), 0)
        PHASE(1, 1, 0, STAGE_A(1, 0, t3), 0)
        PHASE(1, 1, 1, STAGE_B(1, 0, t3), 1)
    }
    asm volatile("s_waitcnt vmcnt(0)" ::: "memory");  // drain stale DMA before LDS freed

    // ---- epilogue: C frag col=lane&15, row=(lane>>4)*4+r
#pragma unroll
    for (int fm = 0; fm < 8; ++fm) {
        const int row0 = bm + wm * 128 + fm * 16 + kb * 4;
#pragma unroll
        for (int fn = 0; fn < 4; ++fn) {
            const int col = bn + wn * 64 + fn * 16 + lr16;
#pragma unroll
            for (int r = 0; r < 4; ++r) {
                float o = acc[fm][fn][r];
                if (EPI == 1) {
                    if (col < DM) o = phi_f(o) * 0.125f;
                    else if (col < 2 * DM) o = phi_f(o);
                }
                if (EPI == 2) {
                    ((float*)Cv)[(size_t)(row0 + r) * N + col] =
                        o + addx[(size_t)(row0 + r) * N + col];
                } else {
                    ((f16*)Cv)[(size_t)(row0 + r) * N + col] = (f16)o;
                }
            }
        }
    }
}

// ---------------- 4. causal dwconv + silu + gate, in-place on upg[.][2048+c] ----
__global__ __launch_bounds__(256) void conv_gate_k(f16* __restrict__ upg,
                                                   const float* __restrict__ cw,
                                                   const float* __restrict__ cb)
{
    const int row = blockIdx.x;
    const int s = row & (SEQL - 1);
    const int c = threadIdx.x * 8;
    float a[8];
    {
        const float4 b0 = *(const float4*)(cb + c);
        const float4 b1 = *(const float4*)(cb + c + 4);
        a[0] = b0.x; a[1] = b0.y; a[2] = b0.z; a[3] = b0.w;
        a[4] = b1.x; a[5] = b1.y; a[6] = b1.z; a[7] = b1.w;
    }
    float tap[8][4];
#pragma unroll
    for (int j = 0; j < 8; ++j)
        *(float4*)tap[j] = *(const float4*)(cw + (size_t)(c + j) * 4);
#pragma unroll
    for (int jt = 0; jt < 4; ++jt) {
        const int sj = s - 3 + jt;
        if (sj >= 0) {
            const f16x8 u = *(const f16x8*)(upg + (size_t)(row - 3 + jt) * 4096 + c);
#pragma unroll
            for (int j = 0; j < 8; ++j) a[j] = fmaf((float)u[j], tap[j][jt], a[j]);
        }
    }
    const f16x8 g = *(const f16x8*)(upg + (size_t)row * 4096 + 2048 + c);
    f16x8 o;
#pragma unroll
    for (int j = 0; j < 8; ++j) o[j] = (f16)(silu_f((float)g[j]) * silu_f(a[j]));
    *(f16x8*)(upg + (size_t)row * 4096 + 2048 + c) = o;
}

// ---------------- 5a. per-chunk outer products: G[b][h][ch] = K^T V -------------
__global__ __launch_bounds__(256) void gscan_g_k(const f16* __restrict__ qkv,
                                                 float* __restrict__ G)
{
    __shared__ float Ks[4096];
    __shared__ float Vs[4096];
    const int t = threadIdx.x, ch = blockIdx.x, h = blockIdx.y, b = blockIdx.z;
    const int r = t >> 2, c16 = (t & 3) * 16;
    const f16* kp = qkv + ((size_t)b * SEQL + ch * 64 + r) * 3072 + DM + h * 64 + c16;
#pragma unroll
    for (int i = 0; i < 2; ++i) {
        const f16x8 kv = *(const f16x8*)(kp + 8 * i);
        const f16x8 vv = *(const f16x8*)(kp + DM + 8 * i);
#pragma unroll
        for (int j = 0; j < 8; ++j) {
            Ks[r * 64 + c16 + 8 * i + j] = (float)kv[j];
            Vs[r * 64 + c16 + 8 * i + j] = (float)vv[j];
        }
    }
    __syncthreads();
    const int d4 = (t >> 4) * 4, e4 = (t & 15) * 4;
    float4 ag[4] = {};
#pragma unroll 4
    for (int c = 0; c < 64; ++c) {
        float ka[4];
        *(float4*)ka = *(const float4*)(Ks + c * 64 + d4);
        const float4 va = *(const float4*)(Vs + c * 64 + e4);
        FMA4(ag[0], ka[0], va);
        FMA4(ag[1], ka[1], va);
        FMA4(ag[2], ka[2], va);
        FMA4(ag[3], ka[3], va);
    }
    float* go = G + (((size_t)b * 16 + h) * 64 + ch) * 4096 + d4 * 64 + e4;
#pragma unroll
    for (int i = 0; i < 4; ++i) *(float4*)(go + i * 64) = ag[i];
}

// ---------------- 5b. in-place exclusive prefix over chunks ---------------------
__global__ __launch_bounds__(256) void gprefix_k(float* __restrict__ G)
{
    const int bh = blockIdx.x >> 4, sl = blockIdx.x & 15;
    const int idx = sl * 256 + threadIdx.x;
    float run = 0.0f;
    float* p = G + (size_t)bh * 64 * 4096 + idx;
#pragma unroll 4
    for (int ch = 0; ch < 64; ++ch) {
        const float g = *p;
        *p = run;
        run += g;
        p += 4096;
    }
}

// ---------------- 5c. per-chunk read: y = q*M_excl + tril(q k^T) v --------------
__global__ __launch_bounds__(256) void gscan_y_k(const f16* __restrict__ qkv,
                                                 const float* __restrict__ G,
                                                 f16* __restrict__ y)
{
    __shared__ float qT[4096];   // qT[d][c]; later scT[e][c]
    __shared__ float Kd[4096];   // Kd[d][e] = K[e][d]
    __shared__ float Vs[4096];
    __shared__ float Ms[4096];
    const int t = threadIdx.x, ch = blockIdx.x, h = blockIdx.y, b = blockIdx.z;
    const int r = t >> 2, c16 = (t & 3) * 16;
    const f16* qp = qkv + ((size_t)b * SEQL + ch * 64 + r) * 3072 + h * 64 + c16;
#pragma unroll
    for (int i = 0; i < 2; ++i) {
        const f16x8 qv = *(const f16x8*)(qp + 8 * i);
        const f16x8 kv = *(const f16x8*)(qp + DM + 8 * i);
        const f16x8 vv = *(const f16x8*)(qp + 2 * DM + 8 * i);
#pragma unroll
        for (int j = 0; j < 8; ++j) {
            qT[(c16 + 8 * i + j) * 64 + r] = (float)qv[j];
            Kd[(c16 + 8 * i + j) * 64 + r] = (float)kv[j];
            Vs[r * 64 + c16 + 8 * i + j] = (float)vv[j];
        }
    }
    const float* mg = G + (((size_t)b * 16 + h) * 64 + ch) * 4096;
#pragma unroll
    for (int i = 0; i < 4; ++i)
        *(float4*)(Ms + t * 16 + 4 * i) = *(const float4*)(mg + t * 16 + 4 * i);
    __syncthreads();

    const int c4 = (t >> 4) * 4, e4 = (t & 15) * 4;
    float sa[4][4] = {}, ya[4][4] = {};
#pragma unroll 2
    for (int d = 0; d < 64; ++d) {
        float a[4], bb[4], m[4];
        *(float4*)a = *(const float4*)(qT + d * 64 + c4);
        *(float4*)bb = *(const float4*)(Kd + d * 64 + e4);
        *(float4*)m = *(const float4*)(Ms + d * 64 + e4);
#pragma unroll
        for (int i = 0; i < 4; ++i)
#pragma unroll
            for (int j = 0; j < 4; ++j) {
                sa[i][j] = fmaf(a[i], bb[j], sa[i][j]);
                ya[i][j] = fmaf(a[i], m[j], ya[i][j]);
            }
    }
#pragma unroll
    for (int i = 0; i < 4; ++i)
#pragma unroll
        for (int j = 0; j < 4; ++j)
            if (e4 + j > c4 + i) sa[i][j] = 0.0f;
    __syncthreads();
#pragma unroll
    for (int i = 0; i < 4; ++i)
#pragma unroll
        for (int j = 0; j < 4; ++j)
            qT[(e4 + j) * 64 + c4 + i] = sa[i][j];
    __syncthreads();
#pragma unroll 2
    for (int e = 0; e < 64; ++e) {
        float a[4], vv[4];
        *(float4*)a = *(const float4*)(qT + e * 64 + c4);
        *(float4*)vv = *(const float4*)(Vs + e * 64 + e4);
#pragma unroll
        for (int i = 0; i < 4; ++i)
#pragma unroll
            for (int j = 0; j < 4; ++j)
                ya[i][j] = fmaf(a[i], vv[j], ya[i][j]);
    }
#pragma unroll
    for (int i = 0; i < 4; ++i) {
        f16x4 o;
        o[0] = (f16)ya[i][0]; o[1] = (f16)ya[i][1];
        o[2] = (f16)ya[i][2]; o[3] = (f16)ya[i][3];
        *(f16x4*)(y + ((size_t)b * SEQL + ch * 64 + c4 + i) * DM + h * 64 + e4) = o;
    }
}

// ---------------- launch --------------------------------------------------------
extern "C" void kernel_launch(void* const* d_in, const int* in_sizes, int n_in,
                              void* d_out, int out_size, void* d_ws, size_t ws_size,
                              hipStream_t stream)
{
    const float* x      = (const float*)d_in[0];
    const float* norm_w = (const float*)d_in[1];
    const float* w_up   = (const float*)d_in[2];
    const float* w_gate = (const float*)d_in[3];
    const float* w_down = (const float*)d_in[4];
    const float* conv_w = (const float*)d_in[5];
    const float* conv_b = (const float*)d_in[6];
    const float* wq     = (const float*)d_in[7];
    const float* wk     = (const float*)d_in[8];
    const float* wv     = (const float*)d_in[9];
    const float* wo     = (const float*)d_in[10];
    float* out = (float*)d_out;

    const size_t BIG_NEED = 247463936ull;
    const bool big = ws_size >= BIG_NEED;

    if (big) {
        char* p = (char*)d_ws;
        f16* upg = (f16*)p;               p += (size_t)NRALL * 4096 * 2;
        f16* hb  = (f16*)p;               p += (size_t)NRALL * DM * 2;
        char* fmtD   = p;                 p += (size_t)64 * 1024 * 64;
        char* fmtQKV = p;                 p += (size_t)32 * 3072 * 64;
        char* fmtO   = p;                 p += (size_t)32 * 1024 * 64;
        f16* xn = (f16*)p;                p += (size_t)NRALL * DM * 2;
        char* fmtUG  = p;
        float* G = (float*)xn;            // overlays xn (dead after up/gate GEMM)
        f16* qkvb = upg;
        f16* yb   = hb;

        rmsnorm_k<<<NRALL, 256, 0, stream>>>(x, norm_w, xn);
        wfmt_all_k<<<640, 256, 0, stream>>>(w_up, w_gate, w_down, wq, wk, wv, wo,
                                            fmtUG, fmtD, fmtQKV, fmtO);

        mg256_k<0><<<16 * 64, 512, 0, stream>>>(xn, DM, fmtUG, upg, 4096, DM, 16, nullptr);
        conv_gate_k<<<NRALL, 256, 0, stream>>>(upg, conv_w, conv_b);
        mg256_k<0><<<4 * 64, 512, 0, stream>>>(upg + 2048, 4096, fmtD, hb, 1024, DI, 4, nullptr);
        mg256_k<1><<<12 * 64, 512, 0, stream>>>(hb, DM, fmtQKV, qkvb, 3072, DM, 12, nullptr);

        gscan_g_k<<<dim3(64, 16, 4), 256, 0, stream>>>(qkvb, G);
        gprefix_k<<<1024, 256, 0, stream>>>(G);
        gscan_y_k<<<dim3(64, 16, 4), 256, 0, stream>>>(qkvb, G, yb);

        mg256_k<2><<<4 * 64, 512, 0, stream>>>(yb, DM, fmtO, out, 1024, DM, 4, x);
    } else {
        // compact per-batch path (~113 MB)
        char* p = (char*)d_ws;
        f16* xn = (f16*)p;                p += (size_t)NRALL * DM * 2;
        f16* upg = (f16*)p;               p += (size_t)SEQL * 4096 * 2;
        f16* hb  = (f16*)p;               p += (size_t)SEQL * DM * 2;
        float* G = (float*)p;             p += (size_t)16 * 64 * 4096 * 4;
        char* fmtUG  = p;                 p += (size_t)32 * 4096 * 64;
        char* fmtD   = p;                 p += (size_t)64 * 1024 * 64;
        char* fmtQKV = p;                 p += (size_t)32 * 3072 * 64;
        char* fmtO   = p;
        f16* qkvb = upg;
        f16* yb   = hb;

        rmsnorm_k<<<NRALL, 256, 0, stream>>>(x, norm_w, xn);
        wfmt_all_k<<<640, 256, 0, stream>>>(w_up, w_gate, w_down, wq, wk, wv, wo,
                                            fmtUG, fmtD, fmtQKV, fmtO);

        for (int b = 0; b < 4; ++b) {
            const f16* xnb = xn + (size_t)b * SEQL * DM;
            mg256_k<0><<<16 * 16, 512, 0, stream>>>(xnb, DM, fmtUG, upg, 4096, DM, 16, nullptr);
            conv_gate_k<<<SEQL, 256, 0, stream>>>(upg, conv_w, conv_b);
            mg256_k<0><<<4 * 16, 512, 0, stream>>>(upg + 2048, 4096, fmtD, hb, 1024, DI, 4, nullptr);
            mg256_k<1><<<12 * 16, 512, 0, stream>>>(hb, DM, fmtQKV, qkvb, 3072, DM, 12, nullptr);
            gscan_g_k<<<dim3(64, 16, 1), 256, 0, stream>>>(qkvb, G);
            gprefix_k<<<256, 256, 0, stream>>>(G);
            gscan_y_k<<<dim3(64, 16, 1), 256, 0, stream>>>(qkvb, G, yb);
            mg256_k<2><<<4 * 16, 512, 0, stream>>>(yb, DM, fmtO,
                                                   out + (size_t)b * SEQL * DM, 1024, DM, 4,
                                                   x + (size_t)b * SEQL * DM);
        }
    }
}

// Round 7
// 613.262 us; speedup vs baseline: 9.2315x; 1.1440x over previous
//
#include <hip/hip_runtime.h>
#include <hip/hip_fp16.h>
#include <cstdint>

// Problem constants (B=4, S=4096, D=1024)
#define NRALL 16384
#define DM    1024
#define DI    2048
#define SEQL  4096

typedef _Float16 f16;
typedef _Float16 f16x8 __attribute__((ext_vector_type(8)));
typedef _Float16 f16x4 __attribute__((ext_vector_type(4)));
typedef float    f32x4 __attribute__((ext_vector_type(4)));

__device__ __forceinline__ float phi_f(float t)  { return t > 0.0f ? t + 1.0f : __expf(t); }
__device__ __forceinline__ float silu_f(float t) { return t / (1.0f + __expf(-t)); }

#define GLDS16(g, l)                                                            \
    __builtin_amdgcn_global_load_lds(                                           \
        (const __attribute__((address_space(1))) void*)(g),                     \
        (__attribute__((address_space(3))) void*)(l), 16, 0, 0)

#define FMA4(dst, s, vv)                      \
    dst.x = fmaf((s), (vv).x, dst.x);         \
    dst.y = fmaf((s), (vv).y, dst.y);         \
    dst.z = fmaf((s), (vv).z, dst.z);         \
    dst.w = fmaf((s), (vv).w, dst.w);

// ---------------- 1. rmsnorm -> f16 --------------------------------------------
__global__ __launch_bounds__(256) void rmsnorm_k(const float* __restrict__ x,
                                                 const float* __restrict__ nw,
                                                 f16* __restrict__ xn)
{
    const int r = blockIdx.x, t = threadIdx.x;
    const float4 v = *(const float4*)(x + (size_t)r * DM + t * 4);
    float s = v.x * v.x + v.y * v.y + v.z * v.z + v.w * v.w;
#pragma unroll
    for (int m = 1; m < 64; m <<= 1) s += __shfl_xor(s, m);
    __shared__ float ws4[4];
    if ((t & 63) == 0) ws4[t >> 6] = s;
    __syncthreads();
    const float tot = ws4[0] + ws4[1] + ws4[2] + ws4[3];
    const float sc = rsqrtf(tot * (1.0f / DM) + 1e-5f);
    const float4 w = *(const float4*)(nw + t * 4);
    f16x4 o;
    o[0] = (f16)(v.x * sc * w.x); o[1] = (f16)(v.y * sc * w.y);
    o[2] = (f16)(v.z * sc * w.z); o[3] = (f16)(v.w * sc * w.w);
    *(f16x4*)(xn + (size_t)r * DM + t * 4) = o;
}

// ---------------- 2. merged weight format (all 7 weights, one launch) -----------
// Layout per (kt, kh): Ntot x 64B; chunk (n, slot) holds 8 f16 of
// k = kt*64 + kh*32 + c2*8 .. +7 where c2 = slot ^ ((n>>1)&3)  (2-way-free swizzle).
__device__ __forceinline__ void wfmt_one(const float* __restrict__ W, char* __restrict__ fmt,
                                         int n, int kt, int Nw, int Ntot, int noff)
{
    const int ng = noff + n;
#pragma unroll
    for (int kh = 0; kh < 2; ++kh) {
        char* o = fmt + ((size_t)(kt * 2 + kh) * Ntot + ng) * 64;
#pragma unroll
        for (int c2 = 0; c2 < 4; ++c2) {
            f16x8 p;
#pragma unroll
            for (int j = 0; j < 8; ++j)
                p[j] = (f16)W[(size_t)(kt * 64 + kh * 32 + c2 * 8 + j) * Nw + n];
            *(f16x8*)(o + ((c2 ^ ((ng >> 1) & 3)) << 4)) = p;
        }
    }
}

__global__ __launch_bounds__(256) void wfmt_all_k(const float* __restrict__ w_up,
                                                  const float* __restrict__ w_gate,
                                                  const float* __restrict__ w_down,
                                                  const float* __restrict__ wq,
                                                  const float* __restrict__ wk,
                                                  const float* __restrict__ wv,
                                                  const float* __restrict__ wo,
                                                  char* __restrict__ fmtUG,
                                                  char* __restrict__ fmtD,
                                                  char* __restrict__ fmtQKV,
                                                  char* __restrict__ fmtO)
{
    int id = blockIdx.x;
    const int t = threadIdx.x;
    if (id < 128) { wfmt_one(w_up,   fmtUG,  (id % 8) * 256 + t, id / 8, DI, 4096, 0);    return; }
    id -= 128;
    if (id < 128) { wfmt_one(w_gate, fmtUG,  (id % 8) * 256 + t, id / 8, DI, 4096, 2048); return; }
    id -= 128;
    if (id < 128) { wfmt_one(w_down, fmtD,   (id % 4) * 256 + t, id / 4, DM, 1024, 0);    return; }
    id -= 128;
    if (id < 64)  { wfmt_one(wq,     fmtQKV, (id % 4) * 256 + t, id / 4, DM, 3072, 0);    return; }
    id -= 64;
    if (id < 64)  { wfmt_one(wk,     fmtQKV, (id % 4) * 256 + t, id / 4, DM, 3072, 1024); return; }
    id -= 64;
    if (id < 64)  { wfmt_one(wv,     fmtQKV, (id % 4) * 256 + t, id / 4, DM, 3072, 2048); return; }
    id -= 64;
    wfmt_one(wo, fmtO, (id % 4) * 256 + t, id / 4, DM, 1024, 0);
}

// ---------------- 3. 256x256 8-phase f16 MFMA GEMM, 1 barrier/phase -------------
// 512 thr = 8 waves (2m x 4n), BK=64, LDS 128KB: {A,B} x 2buf x 2 k-halves.
// Phase (p, ks, mh): mh0 reads af[fm0-3]+bf[fn0-3] (8 ds_read), mh1 reads af[fm4-7]
// (4 ds_read, bf reused from regs); 16 MFMA each. ONE s_barrier per phase: a wave
// finishing MFMA early issues next phase's reads/stages while others still MFMA.
// Safety: stage at phase p touches only slots whose last reader <= p-2 (in-flight
// reads can only be from phases p, p-1). Stage map (all distances exactly 2):
//  ph1:B1k1<-t1 ph2:A1k1<-t1 ph3:B0k0<-t2 ph4:A0k0<-t2+vm ph5:B0k1<-t2
//  ph6:A0k1<-t2 ph7:B1k0<-t3 ph8:A1k0<-t3+vm
// vmcnt(4) at ph4/ph8 confirms stages >=2 phases old before their first readers.
#define PHASE(p, ks, mh, STAGE_STMT, VM)                                          \
    {                                                                             \
        if ((mh) == 0) {                                                          \
            _Pragma("unroll")                                                     \
            for (int q = 0; q < 4; ++q) {                                         \
                const int row = wm * 128 + q * 16 + lr16;                         \
                af[q] = *(const f16x8*)(ldsb + (p) * 32768 + (ks) * 16384         \
                          + row * 64 + ((kb ^ ((row >> 1) & 3)) << 4));           \
                const int n = wn * 64 + q * 16 + lr16;                            \
                bf[q] = *(const f16x8*)(ldsb + 65536 + (p) * 32768 + (ks) * 16384 \
                          + n * 64 + ((kb ^ ((n >> 1) & 3)) << 4));               \
            }                                                                     \
        } else {                                                                  \
            _Pragma("unroll")                                                     \
            for (int q = 0; q < 4; ++q) {                                         \
                const int row = wm * 128 + (q + 4) * 16 + lr16;                   \
                af[q] = *(const f16x8*)(ldsb + (p) * 32768 + (ks) * 16384         \
                          + row * 64 + ((kb ^ ((row >> 1) & 3)) << 4));           \
            }                                                                     \
        }                                                                         \
        STAGE_STMT;                                                               \
        if (VM) asm volatile("s_waitcnt vmcnt(4)" ::: "memory");                  \
        __builtin_amdgcn_sched_barrier(0);                                        \
        __builtin_amdgcn_s_barrier();                                             \
        asm volatile("s_waitcnt lgkmcnt(0)" ::: "memory");                        \
        __builtin_amdgcn_sched_barrier(0);                                        \
        __builtin_amdgcn_s_setprio(1);                                            \
        _Pragma("unroll")                                                         \
        for (int q = 0; q < 4; ++q) {                                             \
            acc[(mh) * 4 + q][0] = __builtin_amdgcn_mfma_f32_16x16x32_f16(        \
                af[q], bf[0], acc[(mh) * 4 + q][0], 0, 0, 0);                     \
            acc[(mh) * 4 + q][1] = __builtin_amdgcn_mfma_f32_16x16x32_f16(        \
                af[q], bf[1], acc[(mh) * 4 + q][1], 0, 0, 0);                     \
            acc[(mh) * 4 + q][2] = __builtin_amdgcn_mfma_f32_16x16x32_f16(        \
                af[q], bf[2], acc[(mh) * 4 + q][2], 0, 0, 0);                     \
            acc[(mh) * 4 + q][3] = __builtin_amdgcn_mfma_f32_16x16x32_f16(        \
                af[q], bf[3], acc[(mh) * 4 + q][3], 0, 0, 0);                     \
        }                                                                         \
        __builtin_amdgcn_s_setprio(0);                                            \
        __builtin_amdgcn_sched_barrier(0);                                        \
    }

template <int EPI>
__global__ __launch_bounds__(512, 2) void mg256_k(const f16* __restrict__ A, int lda,
                                                  const char* __restrict__ fmt,
                                                  void* __restrict__ Cv,
                                                  int N, int K, int gx,
                                                  const float* __restrict__ addx)
{
    __shared__ __align__(16) char ldsb[131072];

    const int t = threadIdx.x;
    int wid = blockIdx.x;
    { const int cpx = gridDim.x >> 3; wid = (wid & 7) * cpx + (wid >> 3); }  // XCD swizzle
    const int bx = wid % gx, by = wid / gx;
    const int bm = by * 256, bn = bx * 256;
    const int lane = t & 63, wv = t >> 6;
    const int wm = wv >> 2, wn = wv & 3;
    const int kb = lane >> 4, lr16 = lane & 15;
    const int NT = K >> 6;

    f32x4 acc[8][4];
#pragma unroll
    for (int i = 0; i < 8; ++i)
#pragma unroll
        for (int j = 0; j < 4; ++j) acc[i][j] = (f32x4)0.0f;

    auto STAGE_A = [&](int p, int kh, int kt) {
#pragma unroll
        for (int r = 0; r < 2; ++r) {
            const int idx = (r * 8 + wv) * 64;
            const int ii = idx + lane;
            const int row = ii >> 2, sl = ii & 3;
            const int c2 = sl ^ ((row >> 1) & 3);
            const f16* src = A + (size_t)(bm + row) * lda + kt * 64 + kh * 32 + c2 * 8;
            GLDS16(src, ldsb + p * 32768 + kh * 16384 + idx * 16);
        }
    };
    auto STAGE_B = [&](int p, int kh, int kt) {
#pragma unroll
        for (int r = 0; r < 2; ++r) {
            const int idx = (r * 8 + wv) * 64;
            const char* src = fmt + ((size_t)(kt * 2 + kh) * N + bn) * 64 + (size_t)(idx + lane) * 16;
            GLDS16(src, ldsb + 65536 + p * 32768 + kh * 16384 + idx * 16);
        }
    };

    // prologue: buf0 <- tile0 (both halves), buf1.kh0 <- tile1; vmcnt(4) -> buf0 landed
    STAGE_A(0, 0, 0); STAGE_B(0, 0, 0);
    STAGE_A(0, 1, 0); STAGE_B(0, 1, 0);
    const int t1p = NT > 1 ? 1 : 0;
    STAGE_A(1, 0, t1p); STAGE_B(1, 0, t1p);
    asm volatile("s_waitcnt vmcnt(4)" ::: "memory");
    __builtin_amdgcn_s_barrier();
    __builtin_amdgcn_sched_barrier(0);

    f16x8 af[4], bf[4];
    const int NI = NT >> 1;
    for (int i = 0; i < NI; ++i) {
        const int t1 = 2 * i + 1;
        const int t2 = 2 * i + 2 < NT ? 2 * i + 2 : NT - 1;
        const int t3 = 2 * i + 3 < NT ? 2 * i + 3 : NT - 1;
        PHASE(0, 0, 0, STAGE_B(1, 1, t1), 0)
        PHASE(0, 0, 1, STAGE_A(1, 1, t1), 0)
        PHASE(0, 1, 0, STAGE_B(0, 0, t2), 0)
        PHASE(0, 1, 1, STAGE_A(0, 0, t2), 1)
        PHASE(1, 0, 0, STAGE_B(0, 1, t2), 0)
        PHASE(1, 0, 1, STAGE_A(0, 1, t2), 0)
        PHASE(1, 1, 0, STAGE_B(1, 0, t3), 0)
        PHASE(1, 1, 1, STAGE_A(1, 0, t3), 1)
    }
    asm volatile("s_waitcnt vmcnt(0)" ::: "memory");  // drain stale DMA before LDS freed

    // ---- epilogue: C frag col=lane&15, row=(lane>>4)*4+r
#pragma unroll
    for (int fm = 0; fm < 8; ++fm) {
        const int row0 = bm + wm * 128 + fm * 16 + kb * 4;
#pragma unroll
        for (int fn = 0; fn < 4; ++fn) {
            const int col = bn + wn * 64 + fn * 16 + lr16;
#pragma unroll
            for (int r = 0; r < 4; ++r) {
                float o = acc[fm][fn][r];
                if (EPI == 1) {
                    if (col < DM) o = phi_f(o) * 0.125f;
                    else if (col < 2 * DM) o = phi_f(o);
                }
                if (EPI == 2) {
                    ((float*)Cv)[(size_t)(row0 + r) * N + col] =
                        o + addx[(size_t)(row0 + r) * N + col];
                } else {
                    ((f16*)Cv)[(size_t)(row0 + r) * N + col] = (f16)o;
                }
            }
        }
    }
}

// ---------------- 4. causal dwconv + silu + gate, rolling window ----------------
// Block = 16 rows x 2048 cols; thread owns 8 cols, rolls a 4-row f16x8 window.
// Reads each up row ~1.19x (vs 4x for the per-row version).
__global__ __launch_bounds__(256) void conv_gate_k(f16* __restrict__ upg,
                                                   const float* __restrict__ cw,
                                                   const float* __restrict__ cb)
{
    const int r0 = blockIdx.x * 16;
    const int c = threadIdx.x * 8;
    float bias[8];
    {
        const float4 b0 = *(const float4*)(cb + c);
        const float4 b1 = *(const float4*)(cb + c + 4);
        bias[0] = b0.x; bias[1] = b0.y; bias[2] = b0.z; bias[3] = b0.w;
        bias[4] = b1.x; bias[5] = b1.y; bias[6] = b1.z; bias[7] = b1.w;
    }
    float tap[8][4];
#pragma unroll
    for (int j = 0; j < 8; ++j)
        *(float4*)tap[j] = *(const float4*)(cw + (size_t)(c + j) * 4);

    const bool lead = (r0 & (SEQL - 1)) == 0;   // block starts a sequence
    f16x8 w0, w1, w2;
    if (lead) {
        w0 = (f16x8)(f16)0; w1 = (f16x8)(f16)0; w2 = (f16x8)(f16)0;
    } else {
        w0 = *(const f16x8*)(upg + (size_t)(r0 - 3) * 4096 + c);
        w1 = *(const f16x8*)(upg + (size_t)(r0 - 2) * 4096 + c);
        w2 = *(const f16x8*)(upg + (size_t)(r0 - 1) * 4096 + c);
    }
#pragma unroll 4
    for (int i = 0; i < 16; ++i) {
        const size_t row = (size_t)(r0 + i);
        const f16x8 w3 = *(const f16x8*)(upg + row * 4096 + c);
        const f16x8 g  = *(const f16x8*)(upg + row * 4096 + 2048 + c);
        f16x8 o;
#pragma unroll
        for (int j = 0; j < 8; ++j) {
            float a = bias[j];
            a = fmaf((float)w0[j], tap[j][0], a);
            a = fmaf((float)w1[j], tap[j][1], a);
            a = fmaf((float)w2[j], tap[j][2], a);
            a = fmaf((float)w3[j], tap[j][3], a);
            o[j] = (f16)(silu_f((float)g[j]) * silu_f(a));
        }
        *(f16x8*)(upg + row * 4096 + 2048 + c) = o;
        w0 = w1; w1 = w2; w2 = w3;
    }
}

// ---------------- 5a. per-chunk outer products: G[b][h][ch] = K^T V -------------
__global__ __launch_bounds__(256) void gscan_g_k(const f16* __restrict__ qkv,
                                                 float* __restrict__ G)
{
    __shared__ float Ks[4096];
    __shared__ float Vs[4096];
    const int t = threadIdx.x, ch = blockIdx.x, h = blockIdx.y, b = blockIdx.z;
    const int r = t >> 2, c16 = (t & 3) * 16;
    const f16* kp = qkv + ((size_t)b * SEQL + ch * 64 + r) * 3072 + DM + h * 64 + c16;
#pragma unroll
    for (int i = 0; i < 2; ++i) {
        const f16x8 kv = *(const f16x8*)(kp + 8 * i);
        const f16x8 vv = *(const f16x8*)(kp + DM + 8 * i);
#pragma unroll
        for (int j = 0; j < 8; ++j) {
            Ks[r * 64 + c16 + 8 * i + j] = (float)kv[j];
            Vs[r * 64 + c16 + 8 * i + j] = (float)vv[j];
        }
    }
    __syncthreads();
    const int d4 = (t >> 4) * 4, e4 = (t & 15) * 4;
    float4 ag[4] = {};
#pragma unroll 4
    for (int c = 0; c < 64; ++c) {
        float ka[4];
        *(float4*)ka = *(const float4*)(Ks + c * 64 + d4);
        const float4 va = *(const float4*)(Vs + c * 64 + e4);
        FMA4(ag[0], ka[0], va);
        FMA4(ag[1], ka[1], va);
        FMA4(ag[2], ka[2], va);
        FMA4(ag[3], ka[3], va);
    }
    float* go = G + (((size_t)b * 16 + h) * 64 + ch) * 4096 + d4 * 64 + e4;
#pragma unroll
    for (int i = 0; i < 4; ++i) *(float4*)(go + i * 64) = ag[i];
}

// ---------------- 5b. in-place exclusive prefix over chunks ---------------------
__global__ __launch_bounds__(256) void gprefix_k(float* __restrict__ G)
{
    const int bh = blockIdx.x >> 4, sl = blockIdx.x & 15;
    const int idx = sl * 256 + threadIdx.x;
    float run = 0.0f;
    float* p = G + (size_t)bh * 64 * 4096 + idx;
#pragma unroll 4
    for (int ch = 0; ch < 64; ++ch) {
        const float g = *p;
        *p = run;
        run += g;
        p += 4096;
    }
}

// ---------------- 5c. per-chunk read: y = q*M_excl + tril(q k^T) v --------------
__global__ __launch_bounds__(256) void gscan_y_k(const f16* __restrict__ qkv,
                                                 const float* __restrict__ G,
                                                 f16* __restrict__ y)
{
    __shared__ float qT[4096];   // qT[d][c]; later scT[e][c]
    __shared__ float Kd[4096];   // Kd[d][e] = K[e][d]
    __shared__ float Vs[4096];
    __shared__ float Ms[4096];
    const int t = threadIdx.x, ch = blockIdx.x, h = blockIdx.y, b = blockIdx.z;
    const int r = t >> 2, c16 = (t & 3) * 16;
    const f16* qp = qkv + ((size_t)b * SEQL + ch * 64 + r) * 3072 + h * 64 + c16;
#pragma unroll
    for (int i = 0; i < 2; ++i) {
        const f16x8 qv = *(const f16x8*)(qp + 8 * i);
        const f16x8 kv = *(const f16x8*)(qp + DM + 8 * i);
        const f16x8 vv = *(const f16x8*)(qp + 2 * DM + 8 * i);
#pragma unroll
        for (int j = 0; j < 8; ++j) {
            qT[(c16 + 8 * i + j) * 64 + r] = (float)qv[j];
            Kd[(c16 + 8 * i + j) * 64 + r] = (float)kv[j];
            Vs[r * 64 + c16 + 8 * i + j] = (float)vv[j];
        }
    }
    const float* mg = G + (((size_t)b * 16 + h) * 64 + ch) * 4096;
#pragma unroll
    for (int i = 0; i < 4; ++i)
        *(float4*)(Ms + t * 16 + 4 * i) = *(const float4*)(mg + t * 16 + 4 * i);
    __syncthreads();

    const int c4 = (t >> 4) * 4, e4 = (t & 15) * 4;
    float sa[4][4] = {}, ya[4][4] = {};
#pragma unroll 2
    for (int d = 0; d < 64; ++d) {
        float a[4], bb[4], m[4];
        *(float4*)a = *(const float4*)(qT + d * 64 + c4);
        *(float4*)bb = *(const float4*)(Kd + d * 64 + e4);
        *(float4*)m = *(const float4*)(Ms + d * 64 + e4);
#pragma unroll
        for (int i = 0; i < 4; ++i)
#pragma unroll
            for (int j = 0; j < 4; ++j) {
                sa[i][j] = fmaf(a[i], bb[j], sa[i][j]);
                ya[i][j] = fmaf(a[i], m[j], ya[i][j]);
            }
    }
#pragma unroll
    for (int i = 0; i < 4; ++i)
#pragma unroll
        for (int j = 0; j < 4; ++j)
            if (e4 + j > c4 + i) sa[i][j] = 0.0f;
    __syncthreads();
#pragma unroll
    for (int i = 0; i < 4; ++i)
#pragma unroll
        for (int j = 0; j < 4; ++j)
            qT[(e4 + j) * 64 + c4 + i] = sa[i][j];
    __syncthreads();
#pragma unroll 2
    for (int e = 0; e < 64; ++e) {
        float a[4], vv[4];
        *(float4*)a = *(const float4*)(qT + e * 64 + c4);
        *(float4*)vv = *(const float4*)(Vs + e * 64 + e4);
#pragma unroll
        for (int i = 0; i < 4; ++i)
#pragma unroll
            for (int j = 0; j < 4; ++j)
                ya[i][j] = fmaf(a[i], vv[j], ya[i][j]);
    }
#pragma unroll
    for (int i = 0; i < 4; ++i) {
        f16x4 o;
        o[0] = (f16)ya[i][0]; o[1] = (f16)ya[i][1];
        o[2] = (f16)ya[i][2]; o[3] = (f16)ya[i][3];
        *(f16x4*)(y + ((size_t)b * SEQL + ch * 64 + c4 + i) * DM + h * 64 + e4) = o;
    }
}

// ---------------- launch --------------------------------------------------------
extern "C" void kernel_launch(void* const* d_in, const int* in_sizes, int n_in,
                              void* d_out, int out_size, void* d_ws, size_t ws_size,
                              hipStream_t stream)
{
    const float* x      = (const float*)d_in[0];
    const float* norm_w = (const float*)d_in[1];
    const float* w_up   = (const float*)d_in[2];
    const float* w_gate = (const float*)d_in[3];
    const float* w_down = (const float*)d_in[4];
    const float* conv_w = (const float*)d_in[5];
    const float* conv_b = (const float*)d_in[6];
    const float* wq     = (const float*)d_in[7];
    const float* wk     = (const float*)d_in[8];
    const float* wv     = (const float*)d_in[9];
    const float* wo     = (const float*)d_in[10];
    float* out = (float*)d_out;

    const size_t BIG_NEED = 247463936ull;
    const bool big = ws_size >= BIG_NEED;

    if (big) {
        char* p = (char*)d_ws;
        f16* upg = (f16*)p;               p += (size_t)NRALL * 4096 * 2;
        f16* hb  = (f16*)p;               p += (size_t)NRALL * DM * 2;
        char* fmtD   = p;                 p += (size_t)64 * 1024 * 64;
        char* fmtQKV = p;                 p += (size_t)32 * 3072 * 64;
        char* fmtO   = p;                 p += (size_t)32 * 1024 * 64;
        f16* xn = (f16*)p;                p += (size_t)NRALL * DM * 2;
        char* fmtUG  = p;
        float* G = (float*)xn;            // overlays xn (dead after up/gate GEMM)
        f16* qkvb = upg;
        f16* yb   = hb;

        rmsnorm_k<<<NRALL, 256, 0, stream>>>(x, norm_w, xn);
        wfmt_all_k<<<640, 256, 0, stream>>>(w_up, w_gate, w_down, wq, wk, wv, wo,
                                            fmtUG, fmtD, fmtQKV, fmtO);

        mg256_k<0><<<16 * 64, 512, 0, stream>>>(xn, DM, fmtUG, upg, 4096, DM, 16, nullptr);
        conv_gate_k<<<NRALL / 16, 256, 0, stream>>>(upg, conv_w, conv_b);
        mg256_k<0><<<4 * 64, 512, 0, stream>>>(upg + 2048, 4096, fmtD, hb, 1024, DI, 4, nullptr);
        mg256_k<1><<<12 * 64, 512, 0, stream>>>(hb, DM, fmtQKV, qkvb, 3072, DM, 12, nullptr);

        gscan_g_k<<<dim3(64, 16, 4), 256, 0, stream>>>(qkvb, G);
        gprefix_k<<<1024, 256, 0, stream>>>(G);
        gscan_y_k<<<dim3(64, 16, 4), 256, 0, stream>>>(qkvb, G, yb);

        mg256_k<2><<<4 * 64, 512, 0, stream>>>(yb, DM, fmtO, out, 1024, DM, 4, x);
    } else {
        // compact per-batch path (~113 MB)
        char* p = (char*)d_ws;
        f16* xn = (f16*)p;                p += (size_t)NRALL * DM * 2;
        f16* upg = (f16*)p;               p += (size_t)SEQL * 4096 * 2;
        f16* hb  = (f16*)p;               p += (size_t)SEQL * DM * 2;
        float* G = (float*)p;             p += (size_t)16 * 64 * 4096 * 4;
        char* fmtUG  = p;                 p += (size_t)32 * 4096 * 64;
        char* fmtD   = p;                 p += (size_t)64 * 1024 * 64;
        char* fmtQKV = p;                 p += (size_t)32 * 3072 * 64;
        char* fmtO   = p;
        f16* qkvb = upg;
        f16* yb   = hb;

        rmsnorm_k<<<NRALL, 256, 0, stream>>>(x, norm_w, xn);
        wfmt_all_k<<<640, 256, 0, stream>>>(w_up, w_gate, w_down, wq, wk, wv, wo,
                                            fmtUG, fmtD, fmtQKV, fmtO);

        for (int b = 0; b < 4; ++b) {
            const f16* xnb = xn + (size_t)b * SEQL * DM;
            mg256_k<0><<<16 * 16, 512, 0, stream>>>(xnb, DM, fmtUG, upg, 4096, DM, 16, nullptr);
            conv_gate_k<<<SEQL / 16, 256, 0, stream>>>(upg, conv_w, conv_b);
            mg256_k<0><<<4 * 16, 512, 0, stream>>>(upg + 2048, 4096, fmtD, hb, 1024, DI, 4, nullptr);
            mg256_k<1><<<12 * 16, 512, 0, stream>>>(hb, DM, fmtQKV, qkvb, 3072, DM, 12, nullptr);
            gscan_g_k<<<dim3(64, 16, 1), 256, 0, stream>>>(qkvb, G);
            gprefix_k<<<256, 256, 0, stream>>>(G);
            gscan_y_k<<<dim3(64, 16, 1), 256, 0, stream>>>(qkvb, G, yb);
            mg256_k<2><<<4 * 16, 512, 0, stream>>>(yb, DM, fmtO,
                                                   out + (size_t)b * SEQL * DM, 1024, DM, 4,
                                                   x + (size_t)b * SEQL * DM);
        }
    }
}

// Round 10
// 612.878 us; speedup vs baseline: 9.2373x; 1.0006x over previous
//
#include <hip/hip_runtime.h>
#include <hip/hip_fp16.h>
#include <cstdint>

// Problem constants (B=4, S=4096, D=1024)
#define NRALL 16384
#define DM    1024
#define DI    2048
#define SEQL  4096

typedef _Float16 f16;
typedef _Float16 f16x8 __attribute__((ext_vector_type(8)));
typedef _Float16 f16x4 __attribute__((ext_vector_type(4)));
typedef float    f32x4 __attribute__((ext_vector_type(4)));

__device__ __forceinline__ float phi_f(float t)  { return t > 0.0f ? t + 1.0f : __expf(t); }
__device__ __forceinline__ float silu_f(float t) { return t / (1.0f + __expf(-t)); }

#define GLDS16(g, l)                                                            \
    __builtin_amdgcn_global_load_lds(                                           \
        (const __attribute__((address_space(1))) void*)(g),                     \
        (__attribute__((address_space(3))) void*)(l), 16, 0, 0)

#define FMA4(dst, s, vv)                      \
    dst.x = fmaf((s), (vv).x, dst.x);         \
    dst.y = fmaf((s), (vv).y, dst.y);         \
    dst.z = fmaf((s), (vv).z, dst.z);         \
    dst.w = fmaf((s), (vv).w, dst.w);

// ---------------- 1. rmsnorm -> f16 --------------------------------------------
__global__ __launch_bounds__(256) void rmsnorm_k(const float* __restrict__ x,
                                                 const float* __restrict__ nw,
                                                 f16* __restrict__ xn)
{
    const int r = blockIdx.x, t = threadIdx.x;
    const float4 v = *(const float4*)(x + (size_t)r * DM + t * 4);
    float s = v.x * v.x + v.y * v.y + v.z * v.z + v.w * v.w;
#pragma unroll
    for (int m = 1; m < 64; m <<= 1) s += __shfl_xor(s, m);
    __shared__ float ws4[4];
    if ((t & 63) == 0) ws4[t >> 6] = s;
    __syncthreads();
    const float tot = ws4[0] + ws4[1] + ws4[2] + ws4[3];
    const float sc = rsqrtf(tot * (1.0f / DM) + 1e-5f);
    const float4 w = *(const float4*)(nw + t * 4);
    f16x4 o;
    o[0] = (f16)(v.x * sc * w.x); o[1] = (f16)(v.y * sc * w.y);
    o[2] = (f16)(v.z * sc * w.z); o[3] = (f16)(v.w * sc * w.w);
    *(f16x4*)(xn + (size_t)r * DM + t * 4) = o;
}

// ---------------- 2. merged weight format (all 7 weights, one launch) -----------
// Layout per (kt, kh): Ntot x 64B; chunk (n, slot) holds 8 f16 of
// k = kt*64 + kh*32 + c2*8 .. +7 where c2 = slot ^ ((n>>1)&3)  (2-way-free swizzle).
__device__ __forceinline__ void wfmt_one(const float* __restrict__ W, char* __restrict__ fmt,
                                         int n, int kt, int Nw, int Ntot, int noff)
{
    const int ng = noff + n;
#pragma unroll
    for (int kh = 0; kh < 2; ++kh) {
        char* o = fmt + ((size_t)(kt * 2 + kh) * Ntot + ng) * 64;
#pragma unroll
        for (int c2 = 0; c2 < 4; ++c2) {
            f16x8 p;
#pragma unroll
            for (int j = 0; j < 8; ++j)
                p[j] = (f16)W[(size_t)(kt * 64 + kh * 32 + c2 * 8 + j) * Nw + n];
            *(f16x8*)(o + ((c2 ^ ((ng >> 1) & 3)) << 4)) = p;
        }
    }
}

__global__ __launch_bounds__(256) void wfmt_all_k(const float* __restrict__ w_up,
                                                  const float* __restrict__ w_gate,
                                                  const float* __restrict__ w_down,
                                                  const float* __restrict__ wq,
                                                  const float* __restrict__ wk,
                                                  const float* __restrict__ wv,
                                                  const float* __restrict__ wo,
                                                  char* __restrict__ fmtUG,
                                                  char* __restrict__ fmtD,
                                                  char* __restrict__ fmtQKV,
                                                  char* __restrict__ fmtO)
{
    int id = blockIdx.x;
    const int t = threadIdx.x;
    if (id < 128) { wfmt_one(w_up,   fmtUG,  (id % 8) * 256 + t, id / 8, DI, 4096, 0);    return; }
    id -= 128;
    if (id < 128) { wfmt_one(w_gate, fmtUG,  (id % 8) * 256 + t, id / 8, DI, 4096, 2048); return; }
    id -= 128;
    if (id < 128) { wfmt_one(w_down, fmtD,   (id % 4) * 256 + t, id / 4, DM, 1024, 0);    return; }
    id -= 128;
    if (id < 64)  { wfmt_one(wq,     fmtQKV, (id % 4) * 256 + t, id / 4, DM, 3072, 0);    return; }
    id -= 64;
    if (id < 64)  { wfmt_one(wk,     fmtQKV, (id % 4) * 256 + t, id / 4, DM, 3072, 1024); return; }
    id -= 64;
    if (id < 64)  { wfmt_one(wv,     fmtQKV, (id % 4) * 256 + t, id / 4, DM, 3072, 2048); return; }
    id -= 64;
    wfmt_one(wo, fmtO, (id % 4) * 256 + t, id / 4, DM, 1024, 0);
}

// ---------------- 3. 256x256 8-phase f16 MFMA GEMM, reg-prefetched --------------
// 512 thr = 8 waves (2m x 4n), BK=64, LDS 128KB: {A,B} x 2buf x 2 k-halves.
// Phase j MFMAs with frags prefetched (ds_read) during phase j-1 -> lgkmcnt(0)
// at phase start waits for reads issued a full phase earlier (latency hidden).
// Hazard calculus (verified per-slot):
//  - frag prefetch for phase j+1 issued at phase j reads slots staged >=5 phases
//    earlier; vmcnt(4) at every odd phase confirms each stage >=1 barrier before
//    its first read (cross-wave RAW safe: reader issues after a barrier that the
//    staging wave's confirming vm precedes).
//  - stage at phase s overwrites a slot whose last frag-read was issued at s-2;
//    that read completed before its wave's lgkmcnt at s-1, which precedes
//    barrier(s-1), which precedes the stage issue at s (cross-wave WAR safe).
// Stage map (iter i computes tiles 2i (buf0), 2i+1 (buf1)):
//  i0:A1k1<-2i+1  i1:B0k0<-2i+2  i2:A0k0<-2i+2  i3:B0k1<-2i+2
//  i4:A0k1<-2i+2  i5:B1k0<-2i+3  i6:A1k0<-2i+3  i7:B1k1<-2i+3
#define PREF_A(aset_, p, ks, rbase)                                               \
    _Pragma("unroll")                                                             \
    for (int q = 0; q < 4; ++q) {                                                 \
        const int row = wm * 128 + ((rbase) + q) * 16 + lr16;                     \
        afr[aset_][q] = *(const f16x8*)(ldsb + (p) * 32768 + (ks) * 16384         \
                        + row * 64 + ((kb ^ ((row >> 1) & 3)) << 4));             \
    }
#define PREF_B(bset_, p, ks)                                                      \
    _Pragma("unroll")                                                             \
    for (int q = 0; q < 4; ++q) {                                                 \
        const int n = wn * 64 + q * 16 + lr16;                                    \
        bfr[bset_][q] = *(const f16x8*)(ldsb + 65536 + (p) * 32768 + (ks) * 16384 \
                        + n * 64 + ((kb ^ ((n >> 1) & 3)) << 4));                 \
    }

#define PHASE(mh, AS, BS, PREF_STMT, STAGE_STMT, VM)                              \
    {                                                                             \
        asm volatile("s_waitcnt lgkmcnt(0)" ::: "memory");                        \
        __builtin_amdgcn_sched_barrier(0);                                        \
        if (VM) {                                                                 \
            asm volatile("s_waitcnt vmcnt(4)" ::: "memory");                      \
            __builtin_amdgcn_sched_barrier(0);                                    \
        }                                                                         \
        PREF_STMT;                                                                \
        STAGE_STMT;                                                               \
        __builtin_amdgcn_sched_barrier(0);                                        \
        __builtin_amdgcn_s_setprio(1);                                            \
        _Pragma("unroll")                                                         \
        for (int q = 0; q < 4; ++q) {                                             \
            acc[(mh) * 4 + q][0] = __builtin_amdgcn_mfma_f32_16x16x32_f16(        \
                afr[AS][q], bfr[BS][0], acc[(mh) * 4 + q][0], 0, 0, 0);           \
            acc[(mh) * 4 + q][1] = __builtin_amdgcn_mfma_f32_16x16x32_f16(        \
                afr[AS][q], bfr[BS][1], acc[(mh) * 4 + q][1], 0, 0, 0);           \
            acc[(mh) * 4 + q][2] = __builtin_amdgcn_mfma_f32_16x16x32_f16(        \
                afr[AS][q], bfr[BS][2], acc[(mh) * 4 + q][2], 0, 0, 0);           \
            acc[(mh) * 4 + q][3] = __builtin_amdgcn_mfma_f32_16x16x32_f16(        \
                afr[AS][q], bfr[BS][3], acc[(mh) * 4 + q][3], 0, 0, 0);           \
        }                                                                         \
        __builtin_amdgcn_s_setprio(0);                                            \
        __builtin_amdgcn_sched_barrier(0);                                        \
        __builtin_amdgcn_s_barrier();                                             \
    }

template <int EPI>
__global__ __launch_bounds__(512, 2) void mg256_k(const f16* __restrict__ A, int lda,
                                                  const char* __restrict__ fmt,
                                                  void* __restrict__ Cv,
                                                  int N, int K, int gx,
                                                  const float* __restrict__ addx)
{
    __shared__ __align__(16) char ldsb[131072];

    const int t = threadIdx.x;
    int wid = blockIdx.x;
    { const int cpx = gridDim.x >> 3; wid = (wid & 7) * cpx + (wid >> 3); }  // XCD swizzle
    const int bx = wid % gx, by = wid / gx;
    const int bm = by * 256, bn = bx * 256;
    const int lane = t & 63, wv = t >> 6;
    const int wm = wv >> 2, wn = wv & 3;
    const int kb = lane >> 4, lr16 = lane & 15;
    const int NT = K >> 6;

    f32x4 acc[8][4];
#pragma unroll
    for (int i = 0; i < 8; ++i)
#pragma unroll
        for (int j = 0; j < 4; ++j) acc[i][j] = (f32x4)0.0f;

    auto STAGE_A = [&](int p, int kh, int kt) {
#pragma unroll
        for (int r = 0; r < 2; ++r) {
            const int idx = (r * 8 + wv) * 64;
            const int ii = idx + lane;
            const int row = ii >> 2, sl = ii & 3;
            const int c2 = sl ^ ((row >> 1) & 3);
            const f16* src = A + (size_t)(bm + row) * lda + kt * 64 + kh * 32 + c2 * 8;
            GLDS16(src, ldsb + p * 32768 + kh * 16384 + idx * 16);
        }
    };
    auto STAGE_B = [&](int p, int kh, int kt) {
#pragma unroll
        for (int r = 0; r < 2; ++r) {
            const int idx = (r * 8 + wv) * 64;
            const char* src = fmt + ((size_t)(kt * 2 + kh) * N + bn) * 64 + (size_t)(idx + lane) * 16;
            GLDS16(src, ldsb + 65536 + p * 32768 + kh * 16384 + idx * 16);
        }
    };

    f16x8 afr[2][4], bfr[2][4];

    // prologue: stage 7 slots (A1k1 is staged in-loop at i0), confirm t0 slots,
    // then prefetch the frags for phase i0.
    const int T1 = NT > 1 ? 1 : 0;
    STAGE_B(0, 0, 0); STAGE_A(0, 0, 0); STAGE_B(0, 1, 0); STAGE_A(0, 1, 0);
    STAGE_B(1, 0, T1); STAGE_A(1, 0, T1); STAGE_B(1, 1, T1);
    asm volatile("s_waitcnt vmcnt(10)" ::: "memory");
    __builtin_amdgcn_s_barrier();
    __builtin_amdgcn_sched_barrier(0);
    PREF_A(0, 0, 0, 0);
    PREF_B(0, 0, 0);

    const int NI = NT >> 1;
    for (int i = 0; i < NI; ++i) {
        const int tc = 2 * i + 1;
        const int ta = 2 * i + 2 < NT ? 2 * i + 2 : NT - 1;
        const int tb = 2 * i + 3 < NT ? 2 * i + 3 : NT - 1;
        PHASE(0, 0, 0, PREF_A(1, 0, 0, 4),                    STAGE_A(1, 1, tc), 0)
        PHASE(1, 1, 0, PREF_A(0, 0, 1, 0); PREF_B(1, 0, 1),   STAGE_B(0, 0, ta), 1)
        PHASE(0, 0, 1, PREF_A(1, 0, 1, 4),                    STAGE_A(0, 0, ta), 0)
        PHASE(1, 1, 1, PREF_A(0, 1, 0, 0); PREF_B(0, 1, 0),   STAGE_B(0, 1, ta), 1)
        PHASE(0, 0, 0, PREF_A(1, 1, 0, 4),                    STAGE_A(0, 1, ta), 0)
        PHASE(1, 1, 0, PREF_A(0, 1, 1, 0); PREF_B(1, 1, 1),   STAGE_B(1, 0, tb), 1)
        PHASE(0, 0, 1, PREF_A(1, 1, 1, 4),                    STAGE_A(1, 0, tb), 0)
        PHASE(1, 1, 1, PREF_A(0, 0, 0, 0); PREF_B(0, 0, 0),   STAGE_B(1, 1, tb), 1)
    }
    asm volatile("s_waitcnt vmcnt(0)" ::: "memory");  // drain DMA before LDS freed

    // ---- epilogue: C frag col=lane&15, row=(lane>>4)*4+r
#pragma unroll
    for (int fm = 0; fm < 8; ++fm) {
        const int row0 = bm + wm * 128 + fm * 16 + kb * 4;
#pragma unroll
        for (int fn = 0; fn < 4; ++fn) {
            const int col = bn + wn * 64 + fn * 16 + lr16;
#pragma unroll
            for (int r = 0; r < 4; ++r) {
                float o = acc[fm][fn][r];
                if (EPI == 1) {
                    if (col < DM) o = phi_f(o) * 0.125f;
                    else if (col < 2 * DM) o = phi_f(o);
                }
                if (EPI == 2) {
                    ((float*)Cv)[(size_t)(row0 + r) * N + col] =
                        o + addx[(size_t)(row0 + r) * N + col];
                } else {
                    ((f16*)Cv)[(size_t)(row0 + r) * N + col] = (f16)o;
                }
            }
        }
    }
}

// ---------------- 4. causal dwconv + silu + gate, rolling window ----------------
__global__ __launch_bounds__(256) void conv_gate_k(f16* __restrict__ upg,
                                                   const float* __restrict__ cw,
                                                   const float* __restrict__ cb)
{
    const int r0 = blockIdx.x * 16;
    const int c = threadIdx.x * 8;
    float bias[8];
    {
        const float4 b0 = *(const float4*)(cb + c);
        const float4 b1 = *(const float4*)(cb + c + 4);
        bias[0] = b0.x; bias[1] = b0.y; bias[2] = b0.z; bias[3] = b0.w;
        bias[4] = b1.x; bias[5] = b1.y; bias[6] = b1.z; bias[7] = b1.w;
    }
    float tap[8][4];
#pragma unroll
    for (int j = 0; j < 8; ++j)
        *(float4*)tap[j] = *(const float4*)(cw + (size_t)(c + j) * 4);

    const bool lead = (r0 & (SEQL - 1)) == 0;
    f16x8 w0, w1, w2;
    if (lead) {
        w0 = (f16x8)(f16)0; w1 = (f16x8)(f16)0; w2 = (f16x8)(f16)0;
    } else {
        w0 = *(const f16x8*)(upg + (size_t)(r0 - 3) * 4096 + c);
        w1 = *(const f16x8*)(upg + (size_t)(r0 - 2) * 4096 + c);
        w2 = *(const f16x8*)(upg + (size_t)(r0 - 1) * 4096 + c);
    }
#pragma unroll 4
    for (int i = 0; i < 16; ++i) {
        const size_t row = (size_t)(r0 + i);
        const f16x8 w3 = *(const f16x8*)(upg + row * 4096 + c);
        const f16x8 g  = *(const f16x8*)(upg + row * 4096 + 2048 + c);
        f16x8 o;
#pragma unroll
        for (int j = 0; j < 8; ++j) {
            float a = bias[j];
            a = fmaf((float)w0[j], tap[j][0], a);
            a = fmaf((float)w1[j], tap[j][1], a);
            a = fmaf((float)w2[j], tap[j][2], a);
            a = fmaf((float)w3[j], tap[j][3], a);
            o[j] = (f16)(silu_f((float)g[j]) * silu_f(a));
        }
        *(f16x8*)(upg + row * 4096 + 2048 + c) = o;
        w0 = w1; w1 = w2; w2 = w3;
    }
}

// ---------------- 5a. per-chunk outer products: G[b][h][ch] = K^T V (f16 out) ---
__global__ __launch_bounds__(256) void gscan_g_k(const f16* __restrict__ qkv,
                                                 f16* __restrict__ G)
{
    __shared__ float Ks[4096];
    __shared__ float Vs[4096];
    const int t = threadIdx.x, ch = blockIdx.x, h = blockIdx.y, b = blockIdx.z;
    const int r = t >> 2, c16 = (t & 3) * 16;
    const f16* kp = qkv + ((size_t)b * SEQL + ch * 64 + r) * 3072 + DM + h * 64 + c16;
#pragma unroll
    for (int i = 0; i < 2; ++i) {
        const f16x8 kv = *(const f16x8*)(kp + 8 * i);
        const f16x8 vv = *(const f16x8*)(kp + DM + 8 * i);
#pragma unroll
        for (int j = 0; j < 8; ++j) {
            Ks[r * 64 + c16 + 8 * i + j] = (float)kv[j];
            Vs[r * 64 + c16 + 8 * i + j] = (float)vv[j];
        }
    }
    __syncthreads();
    const int d4 = (t >> 4) * 4, e4 = (t & 15) * 4;
    float4 ag[4] = {};
#pragma unroll 4
    for (int c = 0; c < 64; ++c) {
        float ka[4];
        *(float4*)ka = *(const float4*)(Ks + c * 64 + d4);
        const float4 va = *(const float4*)(Vs + c * 64 + e4);
        FMA4(ag[0], ka[0], va);
        FMA4(ag[1], ka[1], va);
        FMA4(ag[2], ka[2], va);
        FMA4(ag[3], ka[3], va);
    }
    f16* go = G + (((size_t)b * 16 + h) * 64 + ch) * 4096 + d4 * 64 + e4;
#pragma unroll
    for (int i = 0; i < 4; ++i) {
        f16x4 o;
        o[0] = (f16)ag[i].x; o[1] = (f16)ag[i].y;
        o[2] = (f16)ag[i].z; o[3] = (f16)ag[i].w;
        *(f16x4*)(go + i * 64) = o;
    }
}

// ---------------- 5b. in-place exclusive prefix over chunks (f16, fp32 carry) ---
__global__ __launch_bounds__(256) void gprefix_k(f16* __restrict__ G)
{
    const int bh = blockIdx.x >> 4, sl = blockIdx.x & 15;
    const int idx = sl * 256 + threadIdx.x;
    float run = 0.0f;
    f16* p = G + (size_t)bh * 64 * 4096 + idx;
#pragma unroll 4
    for (int ch = 0; ch < 64; ++ch) {
        const float g = (float)*p;
        *p = (f16)run;
        run += g;
        p += 4096;
    }
}

// ---------------- 5c. per-chunk read: y = q*M_excl + tril(q k^T) v --------------
__global__ __launch_bounds__(256) void gscan_y_k(const f16* __restrict__ qkv,
                                                 const f16* __restrict__ G,
                                                 f16* __restrict__ y)
{
    __shared__ float qT[4096];   // qT[d][c]; later scT[e][c]
    __shared__ float Kd[4096];   // Kd[d][e] = K[e][d]
    __shared__ float Vs[4096];
    __shared__ float Ms[4096];
    const int t = threadIdx.x, ch = blockIdx.x, h = blockIdx.y, b = blockIdx.z;
    const int r = t >> 2, c16 = (t & 3) * 16;
    const f16* qp = qkv + ((size_t)b * SEQL + ch * 64 + r) * 3072 + h * 64 + c16;
#pragma unroll
    for (int i = 0; i < 2; ++i) {
        const f16x8 qv = *(const f16x8*)(qp + 8 * i);
        const f16x8 kv = *(const f16x8*)(qp + DM + 8 * i);
        const f16x8 vv = *(const f16x8*)(qp + 2 * DM + 8 * i);
#pragma unroll
        for (int j = 0; j < 8; ++j) {
            qT[(c16 + 8 * i + j) * 64 + r] = (float)qv[j];
            Kd[(c16 + 8 * i + j) * 64 + r] = (float)kv[j];
            Vs[r * 64 + c16 + 8 * i + j] = (float)vv[j];
        }
    }
    const f16* mg = G + (((size_t)b * 16 + h) * 64 + ch) * 4096;
#pragma unroll
    for (int i = 0; i < 2; ++i) {
        const f16x8 mv = *(const f16x8*)(mg + t * 16 + 8 * i);
#pragma unroll
        for (int j = 0; j < 8; ++j) Ms[t * 16 + 8 * i + j] = (float)mv[j];
    }
    __syncthreads();

    const int c4 = (t >> 4) * 4, e4 = (t & 15) * 4;
    float sa[4][4] = {}, ya[4][4] = {};
#pragma unroll 2
    for (int d = 0; d < 64; ++d) {
        float a[4], bb[4], m[4];
        *(float4*)a = *(const float4*)(qT + d * 64 + c4);
        *(float4*)bb = *(const float4*)(Kd + d * 64 + e4);
        *(float4*)m = *(const float4*)(Ms + d * 64 + e4);
#pragma unroll
        for (int i = 0; i < 4; ++i)
#pragma unroll
            for (int j = 0; j < 4; ++j) {
                sa[i][j] = fmaf(a[i], bb[j], sa[i][j]);
                ya[i][j] = fmaf(a[i], m[j], ya[i][j]);
            }
    }
#pragma unroll
    for (int i = 0; i < 4; ++i)
#pragma unroll
        for (int j = 0; j < 4; ++j)
            if (e4 + j > c4 + i) sa[i][j] = 0.0f;
    __syncthreads();
#pragma unroll
    for (int i = 0; i < 4; ++i)
#pragma unroll
        for (int j = 0; j < 4; ++j)
            qT[(e4 + j) * 64 + c4 + i] = sa[i][j];
    __syncthreads();
#pragma unroll 2
    for (int e = 0; e < 64; ++e) {
        float a[4], vv[4];
        *(float4*)a = *(const float4*)(qT + e * 64 + c4);
        *(float4*)vv = *(const float4*)(Vs + e * 64 + e4);
#pragma unroll
        for (int i = 0; i < 4; ++i)
#pragma unroll
            for (int j = 0; j < 4; ++j)
                ya[i][j] = fmaf(a[i], vv[j], ya[i][j]);
    }
#pragma unroll
    for (int i = 0; i < 4; ++i) {
        f16x4 o;
        o[0] = (f16)ya[i][0]; o[1] = (f16)ya[i][1];
        o[2] = (f16)ya[i][2]; o[3] = (f16)ya[i][3];
        *(f16x4*)(y + ((size_t)b * SEQL + ch * 64 + c4 + i) * DM + h * 64 + e4) = o;
    }
}

// ---------------- launch --------------------------------------------------------
extern "C" void kernel_launch(void* const* d_in, const int* in_sizes, int n_in,
                              void* d_out, int out_size, void* d_ws, size_t ws_size,
                              hipStream_t stream)
{
    const float* x      = (const float*)d_in[0];
    const float* norm_w = (const float*)d_in[1];
    const float* w_up   = (const float*)d_in[2];
    const float* w_gate = (const float*)d_in[3];
    const float* w_down = (const float*)d_in[4];
    const float* conv_w = (const float*)d_in[5];
    const float* conv_b = (const float*)d_in[6];
    const float* wq     = (const float*)d_in[7];
    const float* wk     = (const float*)d_in[8];
    const float* wv     = (const float*)d_in[9];
    const float* wo     = (const float*)d_in[10];
    float* out = (float*)d_out;

    const size_t BIG_NEED = 247463936ull;
    const bool big = ws_size >= BIG_NEED;

    if (big) {
        char* p = (char*)d_ws;
        f16* upg = (f16*)p;               p += (size_t)NRALL * 4096 * 2;
        f16* hb  = (f16*)p;               p += (size_t)NRALL * DM * 2;
        char* fmtD   = p;                 p += (size_t)64 * 1024 * 64;
        char* fmtQKV = p;                 p += (size_t)32 * 3072 * 64;
        char* fmtO   = p;                 p += (size_t)32 * 1024 * 64;
        f16* xn = (f16*)p;                p += (size_t)NRALL * DM * 2;
        char* fmtUG  = p;
        f16* G = (f16*)xn;                // overlays xn+fmtUG (dead after up/gate GEMM)
        f16* qkvb = upg;
        f16* yb   = hb;

        rmsnorm_k<<<NRALL, 256, 0, stream>>>(x, norm_w, xn);
        wfmt_all_k<<<640, 256, 0, stream>>>(w_up, w_gate, w_down, wq, wk, wv, wo,
                                            fmtUG, fmtD, fmtQKV, fmtO);

        mg256_k<0><<<16 * 64, 512, 0, stream>>>(xn, DM, fmtUG, upg, 4096, DM, 16, nullptr);
        conv_gate_k<<<NRALL / 16, 256, 0, stream>>>(upg, conv_w, conv_b);
        mg256_k<0><<<4 * 64, 512, 0, stream>>>(upg + 2048, 4096, fmtD, hb, 1024, DI, 4, nullptr);
        mg256_k<1><<<12 * 64, 512, 0, stream>>>(hb, DM, fmtQKV, qkvb, 3072, DM, 12, nullptr);

        gscan_g_k<<<dim3(64, 16, 4), 256, 0, stream>>>(qkvb, G);
        gprefix_k<<<1024, 256, 0, stream>>>(G);
        gscan_y_k<<<dim3(64, 16, 4), 256, 0, stream>>>(qkvb, G, yb);

        mg256_k<2><<<4 * 64, 512, 0, stream>>>(yb, DM, fmtO, out, 1024, DM, 4, x);
    } else {
        // compact per-batch path
        char* p = (char*)d_ws;
        f16* xn = (f16*)p;                p += (size_t)NRALL * DM * 2;
        f16* upg = (f16*)p;               p += (size_t)SEQL * 4096 * 2;
        f16* hb  = (f16*)p;               p += (size_t)SEQL * DM * 2;
        f16* G = (f16*)p;                 p += (size_t)16 * 64 * 4096 * 2;
        char* fmtUG  = p;                 p += (size_t)32 * 4096 * 64;
        char* fmtD   = p;                 p += (size_t)64 * 1024 * 64;
        char* fmtQKV = p;                 p += (size_t)32 * 3072 * 64;
        char* fmtO   = p;
        f16* qkvb = upg;
        f16* yb   = hb;

        rmsnorm_k<<<NRALL, 256, 0, stream>>>(x, norm_w, xn);
        wfmt_all_k<<<640, 256, 0, stream>>>(w_up, w_gate, w_down, wq, wk, wv, wo,
                                            fmtUG, fmtD, fmtQKV, fmtO);

        for (int b = 0; b < 4; ++b) {
            const f16* xnb = xn + (size_t)b * SEQL * DM;
            mg256_k<0><<<16 * 16, 512, 0, stream>>>(xnb, DM, fmtUG, upg, 4096, DM, 16, nullptr);
            conv_gate_k<<<SEQL / 16, 256, 0, stream>>>(upg, conv_w, conv_b);
            mg256_k<0><<<4 * 16, 512, 0, stream>>>(upg + 2048, 4096, fmtD, hb, 1024, DI, 4, nullptr);
            mg256_k<1><<<12 * 16, 512, 0, stream>>>(hb, DM, fmtQKV, qkvb, 3072, DM, 12, nullptr);
            gscan_g_k<<<dim3(64, 16, 1), 256, 0, stream>>>(qkvb, G);
            gprefix_k<<<256, 256, 0, stream>>>(G);
            gscan_y_k<<<dim3(64, 16, 1), 256, 0, stream>>>(qkvb, G, yb);
            mg256_k<2><<<4 * 16, 512, 0, stream>>>(yb, DM, fmtO,
                                                   out + (size_t)b * SEQL * DM, 1024, DM, 4,
                                                   x + (size_t)b * SEQL * DM);
        }
    }
}